// Round 1
// baseline (1638.973 us; speedup 1.0000x reference)
//
#include <hip/hip_runtime.h>
#include <cstdint>
#include <cstddef>

#define D_DIM 320
#define NEGINF (-1e30f)

__device__ __forceinline__ const float* zrow(const float* __restrict__ z1,
                                             const float* __restrict__ z2,
                                             int b, int T, int r) {
  return (r < T) ? (z1 + ((size_t)b * T + r) * D_DIM)
                 : (z2 + ((size_t)b * T + (r - T)) * D_DIM);
}

__global__ void zero_out_kernel(float* out, int n) {
  int i = blockIdx.x * blockDim.x + threadIdx.x;
  if (i < n) out[i] = 0.f;
}

// ---------------- instance loss: one block per t ----------------
// rows 0..7 = z1[i][t], rows 8..15 = z2[i-8][t]; sim 16x16; LSE over off-diag.
__global__ __launch_bounds__(256) void instance_kernel(
    const float* __restrict__ z1, const float* __restrict__ z2,
    int T, float scale, float* __restrict__ out) {
  int t = blockIdx.x;
  int tid = threadIdx.x;
  __shared__ float Zs[16][321];
  __shared__ float Ss[16][17];
  __shared__ float Ls[16];

  for (int idx = tid; idx < 16 * D_DIM; idx += 256) {
    int i = idx / D_DIM, d = idx % D_DIM;
    const float* p = (i < 8) ? (z1 + ((size_t)i * T + t) * D_DIM)
                             : (z2 + ((size_t)(i - 8) * T + t) * D_DIM);
    Zs[i][d] = p[d];
  }
  __syncthreads();

  int i = tid >> 4, j = tid & 15;
  float dot = 0.f;
  for (int k = 0; k < D_DIM; ++k) dot += Zs[i][k] * Zs[j][k];
  Ss[i][j] = dot;
  __syncthreads();

  if (tid < 16) {
    int r = tid;
    float m = NEGINF;
    for (int c = 0; c < 16; ++c) if (c != r) m = fmaxf(m, Ss[r][c]);
    float s = 0.f;
    for (int c = 0; c < 16; ++c) if (c != r) s += __expf(Ss[r][c] - m);
    int pos = (r < 8) ? r + 8 : r - 8;
    Ls[r] = m + logf(s) - Ss[r][pos];
  }
  __syncthreads();
  if (tid == 0) {
    float sum = 0.f;
    for (int r = 0; r < 16; ++r) sum += Ls[r];
    atomicAdd(out, sum * scale);
  }
}

// ---------------- temporal loss: fused GEMM + online LSE ----------------
// Block: 256 threads, 64 rows (of N=2T) x all cols in 64-wide tiles.
// thread (tx=tid&15, ty=tid>>4) owns rows ty*4+q, cols tx*4+p of each tile.
__global__ __launch_bounds__(256) void temporal_kernel(
    const float* __restrict__ z1, const float* __restrict__ z2,
    int T, float scale, float* __restrict__ out) {
  int b = blockIdx.y;
  int N = 2 * T;
  int row0 = blockIdx.x * 64;
  int tid = threadIdx.x;
  int tx = tid & 15, ty = tid >> 4;

  __shared__ float As[32][68];
  __shared__ float Bs[32][68];
  __shared__ float posv[64];
  __shared__ float bsum;

  float m_run[4], s_run[4];
#pragma unroll
  for (int q = 0; q < 4; ++q) { m_run[q] = NEGINF; s_run[q] = 0.f; }
  if (tid == 0) bsum = 0.f;
  if (tid < 64) posv[tid] = 0.f;

  int ntiles = (N + 63) >> 6;
  for (int jt = 0; jt < ntiles; ++jt) {
    int col0 = jt << 6;
    float acc[4][4];
#pragma unroll
    for (int q = 0; q < 4; ++q)
#pragma unroll
      for (int p = 0; p < 4; ++p) acc[q][p] = 0.f;

    for (int kk = 0; kk < D_DIM; kk += 32) {
      __syncthreads();
      int rl = tid >> 2;          // 0..63
      int kb = (tid & 3) << 3;    // 0,8,16,24
      {
        int r = row0 + rl;
        float4 v0 = make_float4(0, 0, 0, 0), v1 = make_float4(0, 0, 0, 0);
        if (r < N) {
          const float* p = zrow(z1, z2, b, T, r) + kk + kb;
          v0 = *(const float4*)p;
          v1 = *(const float4*)(p + 4);
        }
        As[kb + 0][rl] = v0.x; As[kb + 1][rl] = v0.y;
        As[kb + 2][rl] = v0.z; As[kb + 3][rl] = v0.w;
        As[kb + 4][rl] = v1.x; As[kb + 5][rl] = v1.y;
        As[kb + 6][rl] = v1.z; As[kb + 7][rl] = v1.w;
      }
      {
        int c = col0 + rl;
        float4 v0 = make_float4(0, 0, 0, 0), v1 = make_float4(0, 0, 0, 0);
        if (c < N) {
          const float* p = zrow(z1, z2, b, T, c) + kk + kb;
          v0 = *(const float4*)p;
          v1 = *(const float4*)(p + 4);
        }
        Bs[kb + 0][rl] = v0.x; Bs[kb + 1][rl] = v0.y;
        Bs[kb + 2][rl] = v0.z; Bs[kb + 3][rl] = v0.w;
        Bs[kb + 4][rl] = v1.x; Bs[kb + 5][rl] = v1.y;
        Bs[kb + 6][rl] = v1.z; Bs[kb + 7][rl] = v1.w;
      }
      __syncthreads();
#pragma unroll
      for (int k = 0; k < 32; ++k) {
        float4 a = *(const float4*)&As[k][ty << 2];
        float4 bb = *(const float4*)&Bs[k][tx << 2];
        float av[4] = {a.x, a.y, a.z, a.w};
        float bv[4] = {bb.x, bb.y, bb.z, bb.w};
#pragma unroll
        for (int q = 0; q < 4; ++q)
#pragma unroll
          for (int p = 0; p < 4; ++p) acc[q][p] += av[q] * bv[p];
      }
    }

    // online-LSE update for this 64-col tile
#pragma unroll
    for (int q = 0; q < 4; ++q) {
      int r = row0 + (ty << 2) + q;
      int pos = (r < T) ? r + T : r - T;
      float v[4];
      float m_loc = NEGINF;
#pragma unroll
      for (int p = 0; p < 4; ++p) {
        int c = col0 + (tx << 2) + p;
        bool valid = (r < N) && (c < N) && (c != r);
        float val = acc[q][p];
        if (valid && c == pos) posv[(ty << 2) + q] = val;
        v[p] = valid ? val : NEGINF;
        m_loc = fmaxf(m_loc, v[p]);
      }
      float s_loc = 0.f;
#pragma unroll
      for (int p = 0; p < 4; ++p) s_loc += __expf(v[p] - m_loc);
      // butterfly combine across the 16 lanes sharing this row group
#pragma unroll
      for (int o = 1; o < 16; o <<= 1) {
        float m2 = __shfl_xor(m_loc, o);
        float s2 = __shfl_xor(s_loc, o);
        float mN = fmaxf(m_loc, m2);
        s_loc = s_loc * __expf(m_loc - mN) + s2 * __expf(m2 - mN);
        m_loc = mN;
      }
      float mN = fmaxf(m_run[q], m_loc);
      s_run[q] = s_run[q] * __expf(m_run[q] - mN) + s_loc * __expf(m_loc - mN);
      m_run[q] = mN;
    }
  }
  __syncthreads();  // posv writes visible

  if (tx == 0) {
    float loss = 0.f;
#pragma unroll
    for (int q = 0; q < 4; ++q) {
      int r = row0 + (ty << 2) + q;
      if (r < N) loss += m_run[q] + logf(s_run[q]) - posv[(ty << 2) + q];
    }
    atomicAdd(&bsum, loss);
  }
  __syncthreads();
  if (tid == 0) atomicAdd(out, bsum * scale);
}

// ---------------- stable argsort of deltas + selection ----------------
// key = (delta<<10)|idx  -> bitonic sort gives jnp stable-argsort semantics.
// keep sorted-rank k iff p[k] < T/2; sel = those k ascending (exactly T/2).
__global__ __launch_bounds__(1024) void sort_sel_kernel(
    const int* __restrict__ time, int T, int* __restrict__ sel) {
  int b = blockIdx.x;
  int tid = threadIdx.x;
  int n = T - 1, half = T >> 1;
  __shared__ unsigned long long keys[1024];
  __shared__ int pfx[1024];

  unsigned long long key = ~0ULL;
  if (tid < n) {
    unsigned d = (unsigned)(time[b * T + tid + 1] - time[b * T + tid]);
    key = ((unsigned long long)d << 10) | (unsigned)tid;
  }
  keys[tid] = key;
  __syncthreads();

  for (int size = 2; size <= 1024; size <<= 1) {
    for (int stride = size >> 1; stride > 0; stride >>= 1) {
      int partner = tid ^ stride;
      if (partner > tid) {
        unsigned long long a = keys[tid], c = keys[partner];
        bool asc = (tid & size) == 0;
        if ((a > c) == asc) { keys[tid] = c; keys[partner] = a; }
      }
      __syncthreads();
    }
  }

  int p = (int)(keys[tid] & 1023ULL);
  int mask = (tid < n && p < half) ? 1 : 0;
  pfx[tid] = mask;
  __syncthreads();
  for (int off = 1; off < 1024; off <<= 1) {
    int t = (tid >= off) ? pfx[tid - off] : 0;
    __syncthreads();
    pfx[tid] += t;
    __syncthreads();
  }
  if (mask) sel[b * half + (pfx[tid] - 1)] = tid;
}

// ---------------- pool (max of adjacent) + gather at sel ----------------
__global__ void pool_kernel(const float* __restrict__ z1, const float* __restrict__ z2,
                            const int* __restrict__ time, const int* __restrict__ sel,
                            float* __restrict__ o1, float* __restrict__ o2,
                            int* __restrict__ otime, int T) {
  int b = blockIdx.y;
  int j = blockIdx.x;
  int half = T >> 1;
  int k = sel[b * half + j];
  const float* a1 = z1 + ((size_t)b * T + k) * D_DIM;
  const float* a2 = z2 + ((size_t)b * T + k) * D_DIM;
  float* d1 = o1 + ((size_t)b * half + j) * D_DIM;
  float* d2 = o2 + ((size_t)b * half + j) * D_DIM;
  for (int d = threadIdx.x; d < D_DIM; d += blockDim.x) {
    d1[d] = fmaxf(a1[d], a1[d + D_DIM]);
    d2[d] = fmaxf(a2[d], a2[d + D_DIM]);
  }
  if (threadIdx.x == 0)
    otime[b * half + j] = (time[b * T + k] + time[b * T + k + 1]) >> 1;
}

extern "C" void kernel_launch(void* const* d_in, const int* in_sizes, int n_in,
                              void* d_out, int out_size, void* d_ws, size_t ws_size,
                              hipStream_t stream) {
  const float* z1_in = (const float*)d_in[0];
  const float* z2_in = (const float*)d_in[1];
  const int* time_in = (const int*)d_in[2];
  float* out = (float*)d_out;
  const int B = 8;

  // workspace carve: ping-pong z buffers (A: T<=512, B: T<=256), times, sel
  char* w = (char*)d_ws;
  size_t zA = (size_t)B * 512 * D_DIM;
  size_t zB = (size_t)B * 256 * D_DIM;
  float* z1A = (float*)w; w += zA * sizeof(float);
  float* z2A = (float*)w; w += zA * sizeof(float);
  float* z1Bb = (float*)w; w += zB * sizeof(float);
  float* z2Bb = (float*)w; w += zB * sizeof(float);
  int* timeA = (int*)w; w += (size_t)B * 512 * sizeof(int);
  int* timeB = (int*)w; w += (size_t)B * 256 * sizeof(int);
  int* sel = (int*)w; w += (size_t)B * 512 * sizeof(int);

  zero_out_kernel<<<1, 64, 0, stream>>>(out, out_size);

  const float* z1c = z1_in;
  const float* z2c = z2_in;
  const int* timec = time_in;
  int T = 1024;
  for (int lvl = 0; lvl < 11; ++lvl) {
    float scale = 1.0f / (352.0f * (float)T);  // 0.5/(2*B*T)/11
    instance_kernel<<<T, 256, 0, stream>>>(z1c, z2c, T, scale, out);
    if (T > 1) {
      int N = 2 * T;
      dim3 g((N + 63) / 64, B);
      temporal_kernel<<<g, 256, 0, stream>>>(z1c, z2c, T, scale, out);
      sort_sel_kernel<<<B, 1024, 0, stream>>>(timec, T, sel);
      float* n1; float* n2; int* nt;
      if ((lvl & 1) == 0) { n1 = z1A; n2 = z2A; nt = timeA; }
      else               { n1 = z1Bb; n2 = z2Bb; nt = timeB; }
      pool_kernel<<<dim3(T / 2, B), 320, 0, stream>>>(z1c, z2c, timec, sel, n1, n2, nt, T);
      z1c = n1; z2c = n2; timec = nt;
      T >>= 1;
    }
  }
}

// Round 2
// 630.325 us; speedup vs baseline: 2.6002x; 2.6002x over previous
//
#include <hip/hip_runtime.h>
#include <cstdint>
#include <cstddef>

#define D_DIM 320
#define NEGINF (-1e30f)

typedef __attribute__((ext_vector_type(8))) short bf16x8_t;
typedef __attribute__((ext_vector_type(4))) float f32x4_t;

__device__ __forceinline__ float bf2f(unsigned short u) {
  union { unsigned int i; float f; } v; v.i = ((unsigned int)u) << 16; return v.f;
}
__device__ __forceinline__ unsigned short f2bf(float f) {
  union { float f; unsigned int i; } u; u.f = f;
  unsigned int b = u.i + 0x7FFFu + ((u.i >> 16) & 1u);
  return (unsigned short)(b >> 16);
}

__device__ __forceinline__ const unsigned short* zrowb(
    const unsigned short* __restrict__ z1, const unsigned short* __restrict__ z2,
    int b, int T, int r) {
  return (r < T) ? (z1 + ((size_t)b * T + r) * D_DIM)
                 : (z2 + ((size_t)b * T + (r - T)) * D_DIM);
}

#define GLOAD_LDS16(SRC, DST)                                                   \
  __builtin_amdgcn_global_load_lds(                                             \
      (const __attribute__((address_space(1))) void*)(SRC),                     \
      (__attribute__((address_space(3))) void*)(DST), 16, 0, 0)

__global__ void zero_out_kernel(float* out, int n) {
  int i = blockIdx.x * blockDim.x + threadIdx.x;
  if (i < n) out[i] = 0.f;
}

// ---------------- fp32 -> bf16 convert ----------------
__global__ void convert_kernel(const float* __restrict__ in,
                               unsigned short* __restrict__ out, int n4) {
  int i = blockIdx.x * blockDim.x + threadIdx.x;
  int stride = gridDim.x * blockDim.x;
  for (int j = i; j < n4; j += stride) {
    float4 v = ((const float4*)in)[j];
    ushort4 r;
    r.x = f2bf(v.x); r.y = f2bf(v.y); r.z = f2bf(v.z); r.w = f2bf(v.w);
    ((ushort4*)out)[j] = r;
  }
}

// ---------------- instance loss: one block per t (bf16 inputs) ----------------
__global__ __launch_bounds__(256) void instance_kernel(
    const unsigned short* __restrict__ z1, const unsigned short* __restrict__ z2,
    int T, float scale, float* __restrict__ out) {
  int t = blockIdx.x;
  int tid = threadIdx.x;
  __shared__ float Zs[16][321];
  __shared__ float Ss[16][17];
  __shared__ float Ls[16];

  for (int idx = tid; idx < 16 * D_DIM; idx += 256) {
    int i = idx / D_DIM, d = idx % D_DIM;
    const unsigned short* p = (i < 8) ? (z1 + ((size_t)i * T + t) * D_DIM)
                                      : (z2 + ((size_t)(i - 8) * T + t) * D_DIM);
    Zs[i][d] = bf2f(p[d]);
  }
  __syncthreads();

  int i = tid >> 4, j = tid & 15;
  float dot = 0.f;
  for (int k = 0; k < D_DIM; ++k) dot += Zs[i][k] * Zs[j][k];
  Ss[i][j] = dot;
  __syncthreads();

  if (tid < 16) {
    int r = tid;
    float m = NEGINF;
    for (int c = 0; c < 16; ++c) if (c != r) m = fmaxf(m, Ss[r][c]);
    float s = 0.f;
    for (int c = 0; c < 16; ++c) if (c != r) s += __expf(Ss[r][c] - m);
    int pos = (r < 8) ? r + 8 : r - 8;
    Ls[r] = m + logf(s) - Ss[r][pos];
  }
  __syncthreads();
  if (tid == 0) {
    float sum = 0.f;
    for (int r = 0; r < 16; ++r) sum += Ls[r];
    atomicAdd(out, sum * scale);
  }
}

// ---------------- temporal loss: MFMA fused GEMM + online LSE ----------------
// 512 threads = 8 waves as 2(row)x4(col); block tile 128 rows x 256-col sweep.
// LDS: A strip [40 planes][128 rows][8 bf16] full-K (80KB),
//      B double-buffered [4 planes][256 cols][8 bf16] (2x16KB).
#define ABASE 0
#define BBASE 5120
__global__ __launch_bounds__(512, 2) void temporal_mfma_kernel(
    const unsigned short* __restrict__ z1, const unsigned short* __restrict__ z2,
    int T, float scale, float* __restrict__ out) {
  int b = blockIdx.y;
  int N = 2 * T;
  int row0 = blockIdx.x * 128;
  int tid = threadIdx.x;
  int w = tid >> 6;
  int lane = tid & 63;
  int lq = lane >> 4, lr = lane & 15;
  int wr = w >> 2, wc = w & 3;

  __shared__ unsigned short lds[(5120 + 2048) * 8];
  __shared__ float mS[4][128];
  __shared__ float sS[4][128];
  __shared__ float bsum;

  if (tid == 0) bsum = 0.f;

  // ---- stage A strip (rows row0..row0+127, 40 planes) ----
  for (int i = 0; i < 10; ++i) {
    int c = w * 10 + i;                 // 0..79
    int p = c >> 1, h = (c & 1) * 64;
    int r = row0 + h + lane;
    if (r > N - 1) r = N - 1;
    const unsigned short* src = zrowb(z1, z2, b, T, r) + p * 8;
    GLOAD_LDS16(src, &lds[(ABASE + p * 128 + h) * 8]);
  }

  int ntiles = (N + 255) >> 8;
  int G = ntiles * 10;

  auto stageB = [&](int g) {
    int cb = (g / 10) * 256;
    int s = g % 10;
    int bb = BBASE + (g & 1) * 1024;
#pragma unroll
    for (int i = 0; i < 2; ++i) {
      int c = w * 2 + i;                // 0..15
      int kg = c >> 2, q = (c & 3) * 64;
      int col = cb + q + lane;
      if (col > N - 1) col = N - 1;
      const unsigned short* src = zrowb(z1, z2, b, T, col) + (s * 4 + kg) * 8;
      GLOAD_LDS16(src, &lds[(bb + kg * 256 + q) * 8]);
    }
  };

  stageB(0);
  __syncthreads();  // drains vmcnt: A + B0 landed

  f32x4_t acc[4][4];
  float mrun[4][4], srun[4][4];
#pragma unroll
  for (int at = 0; at < 4; ++at)
#pragma unroll
    for (int rg = 0; rg < 4; ++rg) { mrun[at][rg] = NEGINF; srun[at][rg] = 0.f; }

  for (int g = 0; g < G; ++g) {
    if (g + 1 < G) stageB(g + 1);
    int s = g % 10;
    if (s == 0) {
#pragma unroll
      for (int at = 0; at < 4; ++at)
#pragma unroll
        for (int ct = 0; ct < 4; ++ct) acc[at][ct] = (f32x4_t)(0.f);
    }
    int bb = BBASE + (g & 1) * 1024;
    bf16x8_t af[4];
#pragma unroll
    for (int at = 0; at < 4; ++at)
      af[at] = *(const bf16x8_t*)&lds[(ABASE + (s * 4 + lq) * 128 + wr * 64 + at * 16 + lr) * 8];
#pragma unroll
    for (int ct = 0; ct < 4; ++ct) {
      bf16x8_t bf = *(const bf16x8_t*)&lds[(bb + lq * 256 + wc * 64 + ct * 16 + lr) * 8];
#pragma unroll
      for (int at = 0; at < 4; ++at)
        acc[at][ct] = __builtin_amdgcn_mfma_f32_16x16x32_bf16(af[at], bf, acc[at][ct], 0, 0, 0);
    }
    if (s == 9) {
      int cb0 = (g / 10) * 256 + wc * 64;
#pragma unroll
      for (int at = 0; at < 4; ++at) {
#pragma unroll
        for (int rg = 0; rg < 4; ++rg) {
          int rr = row0 + wr * 64 + at * 16 + lq * 4 + rg;
          float v[4];
#pragma unroll
          for (int ct = 0; ct < 4; ++ct) {
            int col = cb0 + ct * 16 + lr;
            float vv = acc[at][ct][rg];
            v[ct] = (col < N && col != rr) ? vv : NEGINF;
          }
          float vm = fmaxf(fmaxf(v[0], v[1]), fmaxf(v[2], v[3]));
          float m0 = mrun[at][rg];
          if (vm > m0) { srun[at][rg] *= __expf(m0 - vm); mrun[at][rg] = vm; m0 = vm; }
          srun[at][rg] += __expf(v[0] - m0) + __expf(v[1] - m0) +
                          __expf(v[2] - m0) + __expf(v[3] - m0);
        }
      }
    }
    __syncthreads();
  }

  // ---- cross-lane combine (16 lanes sharing lq), then write per-wave state ----
#pragma unroll
  for (int at = 0; at < 4; ++at) {
#pragma unroll
    for (int rg = 0; rg < 4; ++rg) {
      float m = mrun[at][rg], sv = srun[at][rg];
#pragma unroll
      for (int o = 1; o < 16; o <<= 1) {
        float m2 = __shfl_xor(m, o);
        float s2 = __shfl_xor(sv, o);
        float mN = fmaxf(m, m2);
        sv = sv * __expf(m - mN) + s2 * __expf(m2 - mN);
        m = mN;
      }
      if (lr == 0) {
        int rl = wr * 64 + at * 16 + lq * 4 + rg;
        mS[wc][rl] = m;
        sS[wc][rl] = sv;
      }
    }
  }
  __syncthreads();

  // ---- cross-wave combine + positive-pair direct dot + loss ----
  if (tid < 128) {
    int rr = row0 + tid;
    if (rr < N) {
      float m = fmaxf(fmaxf(mS[0][tid], mS[1][tid]), fmaxf(mS[2][tid], mS[3][tid]));
      float sv = 0.f;
#pragma unroll
      for (int k = 0; k < 4; ++k) sv += sS[k][tid] * __expf(mS[k][tid] - m);
      int pos = (rr < T) ? rr + T : rr - T;
      const unsigned short* za = zrowb(z1, z2, b, T, rr);
      const unsigned short* zp = zrowb(z1, z2, b, T, pos);
      float dot = 0.f;
      for (int k = 0; k < D_DIM; ++k) dot += bf2f(za[k]) * bf2f(zp[k]);
      atomicAdd(&bsum, m + logf(sv) - dot);
    }
  }
  __syncthreads();
  if (tid == 0) atomicAdd(out, bsum * scale);
}

// ---------------- stable argsort of deltas + selection ----------------
__global__ __launch_bounds__(1024) void sort_sel_kernel(
    const int* __restrict__ time, int T, int* __restrict__ sel) {
  int b = blockIdx.x;
  int tid = threadIdx.x;
  int n = T - 1, half = T >> 1;
  __shared__ unsigned long long keys[1024];
  __shared__ int pfx[1024];

  unsigned long long key = ~0ULL;
  if (tid < n) {
    unsigned d = (unsigned)(time[b * T + tid + 1] - time[b * T + tid]);
    key = ((unsigned long long)d << 10) | (unsigned)tid;
  }
  keys[tid] = key;
  __syncthreads();

  for (int size = 2; size <= 1024; size <<= 1) {
    for (int stride = size >> 1; stride > 0; stride >>= 1) {
      int partner = tid ^ stride;
      if (partner > tid) {
        unsigned long long a = keys[tid], c = keys[partner];
        bool asc = (tid & size) == 0;
        if ((a > c) == asc) { keys[tid] = c; keys[partner] = a; }
      }
      __syncthreads();
    }
  }

  int p = (int)(keys[tid] & 1023ULL);
  int mask = (tid < n && p < half) ? 1 : 0;
  pfx[tid] = mask;
  __syncthreads();
  for (int off = 1; off < 1024; off <<= 1) {
    int t = (tid >= off) ? pfx[tid - off] : 0;
    __syncthreads();
    pfx[tid] += t;
    __syncthreads();
  }
  if (mask) sel[b * half + (pfx[tid] - 1)] = tid;
}

// ---------------- pool (max of adjacent) + gather at sel (bf16) ----------------
__global__ void pool_kernel(const unsigned short* __restrict__ z1,
                            const unsigned short* __restrict__ z2,
                            const int* __restrict__ time, const int* __restrict__ sel,
                            unsigned short* __restrict__ o1, unsigned short* __restrict__ o2,
                            int* __restrict__ otime, int T) {
  int b = blockIdx.y;
  int j = blockIdx.x;
  int half = T >> 1;
  int k = sel[b * half + j];
  const unsigned short* a1 = z1 + ((size_t)b * T + k) * D_DIM;
  const unsigned short* a2 = z2 + ((size_t)b * T + k) * D_DIM;
  unsigned short* d1 = o1 + ((size_t)b * half + j) * D_DIM;
  unsigned short* d2 = o2 + ((size_t)b * half + j) * D_DIM;
  for (int d = threadIdx.x; d < D_DIM; d += blockDim.x) {
    unsigned short ua = a1[d], ub = a1[d + D_DIM];
    d1[d] = (bf2f(ua) >= bf2f(ub)) ? ua : ub;
    unsigned short va = a2[d], vb = a2[d + D_DIM];
    d2[d] = (bf2f(va) >= bf2f(vb)) ? va : vb;
  }
  if (threadIdx.x == 0)
    otime[b * half + j] = (time[b * T + k] + time[b * T + k + 1]) >> 1;
}

extern "C" void kernel_launch(void* const* d_in, const int* in_sizes, int n_in,
                              void* d_out, int out_size, void* d_ws, size_t ws_size,
                              hipStream_t stream) {
  const float* z1_in = (const float*)d_in[0];
  const float* z2_in = (const float*)d_in[1];
  const int* time_in = (const int*)d_in[2];
  float* out = (float*)d_out;
  const int B = 8;

  // workspace carve (bf16 buffers): level0 (1024), ping A (512), ping B (256)
  char* w = (char*)d_ws;
  size_t n0 = (size_t)B * 1024 * D_DIM;
  size_t nA = (size_t)B * 512 * D_DIM;
  size_t nB = (size_t)B * 256 * D_DIM;
  unsigned short* zb1_0 = (unsigned short*)w; w += n0 * 2;
  unsigned short* zb2_0 = (unsigned short*)w; w += n0 * 2;
  unsigned short* zb1_A = (unsigned short*)w; w += nA * 2;
  unsigned short* zb2_A = (unsigned short*)w; w += nA * 2;
  unsigned short* zb1_B = (unsigned short*)w; w += nB * 2;
  unsigned short* zb2_B = (unsigned short*)w; w += nB * 2;
  int* timeA = (int*)w; w += (size_t)B * 512 * sizeof(int);
  int* timeB = (int*)w; w += (size_t)B * 256 * sizeof(int);
  int* sel = (int*)w; w += (size_t)B * 512 * sizeof(int);

  zero_out_kernel<<<1, 64, 0, stream>>>(out, out_size);
  convert_kernel<<<2048, 256, 0, stream>>>(z1_in, zb1_0, (int)(n0 / 4));
  convert_kernel<<<2048, 256, 0, stream>>>(z2_in, zb2_0, (int)(n0 / 4));

  const unsigned short* z1c = zb1_0;
  const unsigned short* z2c = zb2_0;
  const int* timec = time_in;
  int T = 1024;
  for (int lvl = 0; lvl < 11; ++lvl) {
    float scale = 1.0f / (352.0f * (float)T);  // 0.5/(2*B*T)/11
    instance_kernel<<<T, 256, 0, stream>>>(z1c, z2c, T, scale, out);
    if (T > 1) {
      int N = 2 * T;
      dim3 g((N + 127) / 128, B);
      temporal_mfma_kernel<<<g, 512, 0, stream>>>(z1c, z2c, T, scale, out);
      sort_sel_kernel<<<B, 1024, 0, stream>>>(timec, T, sel);
      unsigned short* p1; unsigned short* p2; int* nt;
      if ((lvl & 1) == 0) { p1 = zb1_A; p2 = zb2_A; nt = timeA; }
      else               { p1 = zb1_B; p2 = zb2_B; nt = timeB; }
      pool_kernel<<<dim3(T / 2, B), 320, 0, stream>>>(z1c, z2c, timec, sel, p1, p2, nt, T);
      z1c = p1; z2c = p2; timec = nt;
      T >>= 1;
    }
  }
}

// Round 3
// 499.849 us; speedup vs baseline: 3.2789x; 1.2610x over previous
//
#include <hip/hip_runtime.h>
#include <cstdint>
#include <cstddef>

#define D_DIM 320
#define NEGINF (-1e30f)

typedef __attribute__((ext_vector_type(8))) short bf16x8_t;
typedef __attribute__((ext_vector_type(4))) float f32x4_t;

__device__ __forceinline__ float bf2f(unsigned short u) {
  union { unsigned int i; float f; } v; v.i = ((unsigned int)u) << 16; return v.f;
}
__device__ __forceinline__ unsigned short f2bf(float f) {
  union { float f; unsigned int i; } u; u.f = f;
  unsigned int b = u.i + 0x7FFFu + ((u.i >> 16) & 1u);
  return (unsigned short)(b >> 16);
}

__device__ __forceinline__ const unsigned short* zrowb(
    const unsigned short* __restrict__ z1, const unsigned short* __restrict__ z2,
    int b, int T, int r) {
  return (r < T) ? (z1 + ((size_t)b * T + r) * D_DIM)
                 : (z2 + ((size_t)b * T + (r - T)) * D_DIM);
}

#define GLOAD_LDS16(SRC, DST)                                                   \
  __builtin_amdgcn_global_load_lds(                                             \
      (const __attribute__((address_space(1))) void*)(SRC),                     \
      (__attribute__((address_space(3))) void*)(DST), 16, 0, 0)

// ---------------- fp32 -> bf16 convert (both arrays) + zero out ----------------
__global__ void convert_kernel(const float* __restrict__ i1, const float* __restrict__ i2,
                               unsigned short* __restrict__ o1, unsigned short* __restrict__ o2,
                               int n4, float* __restrict__ out, int outn) {
  int i = blockIdx.x * blockDim.x + threadIdx.x;
  if (i < outn) out[i] = 0.f;
  int stride = gridDim.x * blockDim.x;
  for (int j = i; j < n4; j += stride) {
    float4 v = ((const float4*)i1)[j];
    ushort4 r;
    r.x = f2bf(v.x); r.y = f2bf(v.y); r.z = f2bf(v.z); r.w = f2bf(v.w);
    ((ushort4*)o1)[j] = r;
    float4 u = ((const float4*)i2)[j];
    ushort4 q;
    q.x = f2bf(u.x); q.y = f2bf(u.y); q.z = f2bf(u.z); q.w = f2bf(u.w);
    ((ushort4*)o2)[j] = q;
  }
}

// ---------------- instance loss: one block per t (bf16 inputs) ----------------
__global__ __launch_bounds__(256) void instance_kernel(
    const unsigned short* __restrict__ z1, const unsigned short* __restrict__ z2,
    int T, float scale, float* __restrict__ out) {
  int t = blockIdx.x;
  int tid = threadIdx.x;
  __shared__ float Zs[16][321];
  __shared__ float Ss[16][17];
  __shared__ float Ls[16];

  for (int idx = tid; idx < 16 * D_DIM; idx += 256) {
    int i = idx / D_DIM, d = idx % D_DIM;
    const unsigned short* p = (i < 8) ? (z1 + ((size_t)i * T + t) * D_DIM)
                                      : (z2 + ((size_t)(i - 8) * T + t) * D_DIM);
    Zs[i][d] = bf2f(p[d]);
  }
  __syncthreads();

  int i = tid >> 4, j = tid & 15;
  float dot = 0.f;
  for (int k = 0; k < D_DIM; ++k) dot += Zs[i][k] * Zs[j][k];
  Ss[i][j] = dot;
  __syncthreads();

  if (tid < 16) {
    int r = tid;
    float m = NEGINF;
    for (int c = 0; c < 16; ++c) if (c != r) m = fmaxf(m, Ss[r][c]);
    float s = 0.f;
    for (int c = 0; c < 16; ++c) if (c != r) s += __expf(Ss[r][c] - m);
    int pos = (r < 8) ? r + 8 : r - 8;
    Ls[r] = m + logf(s) - Ss[r][pos];
  }
  __syncthreads();
  if (tid == 0) {
    float sum = 0.f;
    for (int r = 0; r < 16; ++r) sum += Ls[r];
    atomicAdd(out, sum * scale);
  }
}

// ---------------- temporal loss: MFMA GEMM + online LSE, col-split partials ----
// grid = (B*S, nrb): linear id % 8 constant per (b,seg) -> same XCD -> B panel
// stays in that XCD's L2. 8 waves as 2(row)x4(col), wave tile 64x64,
// block tile 128 rows x 256-col chunks, BK=64 per phase (8 planes), B dbuf.
// LDS: A [40 planes][128 rows] (80KB) + B 2x[8 planes][256 cols] (64KB).
#define ABASE 0
#define BBASE 5120
#define BBUF 2048
#define MAXS 4
#define WSROW 2048
__global__ __launch_bounds__(512, 1) void temporal_mfma_kernel(
    const unsigned short* __restrict__ z1, const unsigned short* __restrict__ z2,
    int T, int S, float* __restrict__ wsm, float* __restrict__ wss) {
  int N = 2 * T;
  int bx = blockIdx.x;
  int b = bx / S, sg = bx % S;
  int row0 = blockIdx.y * 128;
  int segw = N / S;
  int col_base = sg * segw;
  int nchunks = (segw + 255) >> 8;
  int tid = threadIdx.x;
  int w = tid >> 6, lane = tid & 63;
  int lq = lane >> 4, lr = lane & 15;
  int wr = w >> 2, wc = w & 3;

  __shared__ __align__(16) unsigned short lds[9216 * 8];
  __shared__ float mS[4][128], sS[4][128];

  // ---- stage A strip: rows row0..row0+127, all 40 planes ----
  for (int i = 0; i < 10; ++i) {
    int c = w * 10 + i;                 // 0..79
    int p = c >> 1, h = (c & 1) * 64;
    int r = row0 + h + lane;
    if (r > N - 1) r = N - 1;
    GLOAD_LDS16(zrowb(z1, z2, b, T, r) + p * 8, &lds[(ABASE + p * 128 + h) * 8]);
  }

  int totalph = nchunks * 5;
  auto stageB = [&](int g) {
    int jt = g / 5, ph = g % 5;
    int cb = col_base + jt * 256;
    unsigned short* bb = &lds[(BBASE + (g & 1) * BBUF) * 8];
#pragma unroll
    for (int i = 0; i < 4; ++i) {
      int c = w * 4 + i;                // 0..31
      int kg = c >> 2, q = (c & 3) * 64;
      int col = cb + q + lane;
      if (col > N - 1) col = N - 1;
      GLOAD_LDS16(zrowb(z1, z2, b, T, col) + (ph * 8 + kg) * 8, &bb[(kg * 256 + q) * 8]);
    }
  };

  stageB(0);
  __syncthreads();  // vmcnt drained: A + B0 landed

  f32x4_t acc[4][4];
  float mrun[4][4], srun[4][4];
#pragma unroll
  for (int at = 0; at < 4; ++at)
#pragma unroll
    for (int rg = 0; rg < 4; ++rg) { mrun[at][rg] = NEGINF; srun[at][rg] = 0.f; }

  for (int g = 0; g < totalph; ++g) {
    int ph = g % 5;
    if (g + 1 < totalph) stageB(g + 1);
    if (ph == 0) {
#pragma unroll
      for (int at = 0; at < 4; ++at)
#pragma unroll
        for (int ct = 0; ct < 4; ++ct) acc[at][ct] = (f32x4_t)(0.f);
    }
    const unsigned short* bb = &lds[(BBASE + (g & 1) * BBUF) * 8];
#pragma unroll
    for (int ks = 0; ks < 2; ++ks) {
      bf16x8_t af[4];
#pragma unroll
      for (int at = 0; at < 4; ++at)
        af[at] = *(const bf16x8_t*)&lds[(ABASE + (ph * 8 + ks * 4 + lq) * 128 + wr * 64 + at * 16 + lr) * 8];
#pragma unroll
      for (int ct = 0; ct < 4; ++ct) {
        bf16x8_t bf = *(const bf16x8_t*)&bb[((ks * 4 + lq) * 256 + wc * 64 + ct * 16 + lr) * 8];
#pragma unroll
        for (int at = 0; at < 4; ++at)
          acc[at][ct] = __builtin_amdgcn_mfma_f32_16x16x32_bf16(af[at], bf, acc[at][ct], 0, 0, 0);
      }
    }
    if (ph == 4) {
      int cb0 = col_base + (g / 5) * 256 + wc * 64;
#pragma unroll
      for (int at = 0; at < 4; ++at) {
#pragma unroll
        for (int rg = 0; rg < 4; ++rg) {
          int rr = row0 + wr * 64 + at * 16 + lq * 4 + rg;
          float v[4];
          float vmax = NEGINF;
#pragma unroll
          for (int ct = 0; ct < 4; ++ct) {
            int col = cb0 + ct * 16 + lr;
            v[ct] = (col < N && col != rr) ? acc[at][ct][rg] : NEGINF;
            vmax = fmaxf(vmax, v[ct]);
          }
          float m0 = mrun[at][rg];
          if (vmax > m0) { srun[at][rg] *= __expf(m0 - vmax); mrun[at][rg] = vmax; m0 = vmax; }
          srun[at][rg] += __expf(v[0] - m0) + __expf(v[1] - m0) +
                          __expf(v[2] - m0) + __expf(v[3] - m0);
        }
      }
    }
    __syncthreads();
  }

  // ---- cross-lane combine (16 lanes over lr), then per-wave state to LDS ----
#pragma unroll
  for (int at = 0; at < 4; ++at) {
#pragma unroll
    for (int rg = 0; rg < 4; ++rg) {
      float m = mrun[at][rg], sv = srun[at][rg];
#pragma unroll
      for (int o = 1; o < 16; o <<= 1) {
        float m2 = __shfl_xor(m, o);
        float s2 = __shfl_xor(sv, o);
        float mN = fmaxf(m, m2);
        sv = sv * __expf(m - mN) + s2 * __expf(m2 - mN);
        m = mN;
      }
      if (lr == 0) {
        int rl = wr * 64 + at * 16 + lq * 4 + rg;
        mS[wc][rl] = m;
        sS[wc][rl] = sv;
      }
    }
  }
  __syncthreads();

  // ---- cross-wave combine, write (m,s) partial for this col segment ----
  if (tid < 128) {
    int rr = row0 + tid;
    if (rr < N) {
      float m = fmaxf(fmaxf(mS[0][tid], mS[1][tid]), fmaxf(mS[2][tid], mS[3][tid]));
      float sv = 0.f;
#pragma unroll
      for (int k = 0; k < 4; ++k) sv += sS[k][tid] * __expf(mS[k][tid] - m);
      size_t idx = (size_t)(b * MAXS + sg) * WSROW + rr;
      wsm[idx] = m;
      wss[idx] = sv;
    }
  }
}

// ---------------- combine partials + positive-pair dot + loss ----------------
__global__ __launch_bounds__(256) void combine_kernel(
    const unsigned short* __restrict__ z1, const unsigned short* __restrict__ z2,
    const float* __restrict__ wsm, const float* __restrict__ wss,
    int T, int S, float scale, float* __restrict__ out) {
  int b = blockIdx.y;
  int N = 2 * T;
  int r = blockIdx.x * 256 + threadIdx.x;
  float loss = 0.f;
  if (r < N) {
    float m = NEGINF;
    for (int s = 0; s < S; ++s)
      m = fmaxf(m, wsm[(size_t)(b * MAXS + s) * WSROW + r]);
    float sv = 0.f;
    for (int s = 0; s < S; ++s) {
      size_t idx = (size_t)(b * MAXS + s) * WSROW + r;
      sv += wss[idx] * __expf(wsm[idx] - m);
    }
    int pos = (r < T) ? r + T : r - T;
    const bf16x8_t* za = (const bf16x8_t*)zrowb(z1, z2, b, T, r);
    const bf16x8_t* zp = (const bf16x8_t*)zrowb(z1, z2, b, T, pos);
    float dot = 0.f;
    for (int k = 0; k < D_DIM / 8; ++k) {
      bf16x8_t a = za[k], p = zp[k];
#pragma unroll
      for (int j = 0; j < 8; ++j)
        dot += bf2f((unsigned short)a[j]) * bf2f((unsigned short)p[j]);
    }
    loss = m + logf(sv) - dot;
  }
  // block reduce: wave shuffle then cross-wave
  float v = loss;
#pragma unroll
  for (int o = 1; o < 64; o <<= 1) v += __shfl_xor(v, o);
  __shared__ float part[4];
  int w = threadIdx.x >> 6;
  if ((threadIdx.x & 63) == 0) part[w] = v;
  __syncthreads();
  if (threadIdx.x == 0)
    atomicAdd(out, (part[0] + part[1] + part[2] + part[3]) * scale);
}

// ---------------- stable argsort of deltas + selection (size-matched) --------
template <int SZ>
__global__ __launch_bounds__(SZ) void sort_sel_kernel(
    const int* __restrict__ time, int T, int* __restrict__ sel) {
  int b = blockIdx.x;
  int tid = threadIdx.x;
  int n = T - 1, half = T >> 1;
  __shared__ unsigned long long keys[SZ];
  __shared__ int pfx[SZ];

  unsigned long long key = ~0ULL;
  if (tid < n) {
    unsigned d = (unsigned)(time[b * T + tid + 1] - time[b * T + tid]);
    key = ((unsigned long long)d << 10) | (unsigned)tid;
  }
  keys[tid] = key;
  __syncthreads();

  for (int size = 2; size <= SZ; size <<= 1) {
    for (int stride = size >> 1; stride > 0; stride >>= 1) {
      int partner = tid ^ stride;
      if (partner > tid) {
        unsigned long long a = keys[tid], c = keys[partner];
        bool asc = (tid & size) == 0;
        if ((a > c) == asc) { keys[tid] = c; keys[partner] = a; }
      }
      __syncthreads();
    }
  }

  int p = (int)(keys[tid] & 1023ULL);
  int mask = (tid < n && p < half) ? 1 : 0;
  pfx[tid] = mask;
  __syncthreads();
  for (int off = 1; off < SZ; off <<= 1) {
    int t = (tid >= off) ? pfx[tid - off] : 0;
    __syncthreads();
    pfx[tid] += t;
    __syncthreads();
  }
  if (mask) sel[b * half + (pfx[tid] - 1)] = tid;
}

// ---------------- pool (max of adjacent) + gather at sel (bf16) ----------------
__global__ void pool_kernel(const unsigned short* __restrict__ z1,
                            const unsigned short* __restrict__ z2,
                            const int* __restrict__ time, const int* __restrict__ sel,
                            unsigned short* __restrict__ o1, unsigned short* __restrict__ o2,
                            int* __restrict__ otime, int T) {
  int b = blockIdx.y;
  int j = blockIdx.x;
  int half = T >> 1;
  int k = sel[b * half + j];
  const unsigned short* a1 = z1 + ((size_t)b * T + k) * D_DIM;
  const unsigned short* a2 = z2 + ((size_t)b * T + k) * D_DIM;
  unsigned short* d1 = o1 + ((size_t)b * half + j) * D_DIM;
  unsigned short* d2 = o2 + ((size_t)b * half + j) * D_DIM;
  for (int d = threadIdx.x; d < D_DIM; d += blockDim.x) {
    unsigned short ua = a1[d], ub = a1[d + D_DIM];
    d1[d] = (bf2f(ua) >= bf2f(ub)) ? ua : ub;
    unsigned short va = a2[d], vb = a2[d + D_DIM];
    d2[d] = (bf2f(va) >= bf2f(vb)) ? va : vb;
  }
  if (threadIdx.x == 0)
    otime[b * half + j] = (time[b * T + k] + time[b * T + k + 1]) >> 1;
}

extern "C" void kernel_launch(void* const* d_in, const int* in_sizes, int n_in,
                              void* d_out, int out_size, void* d_ws, size_t ws_size,
                              hipStream_t stream) {
  const float* z1_in = (const float*)d_in[0];
  const float* z2_in = (const float*)d_in[1];
  const int* time_in = (const int*)d_in[2];
  float* out = (float*)d_out;
  const int B = 8;

  // workspace carve (bf16 buffers): level0 (1024), ping A (512), ping B (256)
  char* w = (char*)d_ws;
  size_t n0 = (size_t)B * 1024 * D_DIM;
  size_t nA = (size_t)B * 512 * D_DIM;
  size_t nB = (size_t)B * 256 * D_DIM;
  unsigned short* zb1_0 = (unsigned short*)w; w += n0 * 2;
  unsigned short* zb2_0 = (unsigned short*)w; w += n0 * 2;
  unsigned short* zb1_A = (unsigned short*)w; w += nA * 2;
  unsigned short* zb2_A = (unsigned short*)w; w += nA * 2;
  unsigned short* zb1_B = (unsigned short*)w; w += nB * 2;
  unsigned short* zb2_B = (unsigned short*)w; w += nB * 2;
  int* timeA = (int*)w; w += (size_t)B * 512 * sizeof(int);
  int* timeB = (int*)w; w += (size_t)B * 256 * sizeof(int);
  int* sel = (int*)w; w += (size_t)B * 512 * sizeof(int);
  float* wsm = (float*)w; w += (size_t)B * MAXS * WSROW * sizeof(float);
  float* wss = (float*)w; w += (size_t)B * MAXS * WSROW * sizeof(float);

  convert_kernel<<<2048, 256, 0, stream>>>(z1_in, z2_in, zb1_0, zb2_0,
                                           (int)(n0 / 4), out, out_size);

  const unsigned short* z1c = zb1_0;
  const unsigned short* z2c = zb2_0;
  const int* timec = time_in;
  int T = 1024;
  for (int lvl = 0; lvl < 11; ++lvl) {
    float scale = 1.0f / (352.0f * (float)T);  // 0.5/(2*B*T)/11
    instance_kernel<<<T, 256, 0, stream>>>(z1c, z2c, T, scale, out);
    if (T > 1) {
      int N = 2 * T;
      int S = (T == 1024) ? 2 : (T == 512) ? 4 : (T == 256) ? 2 : 1;
      dim3 tg(B * S, (N + 127) / 128);
      temporal_mfma_kernel<<<tg, 512, 0, stream>>>(z1c, z2c, T, S, wsm, wss);
      dim3 cg((N + 255) / 256, B);
      combine_kernel<<<cg, 256, 0, stream>>>(z1c, z2c, wsm, wss, T, S, scale, out);

      switch (T) {
        case 1024: sort_sel_kernel<1024><<<B, 1024, 0, stream>>>(timec, T, sel); break;
        case 512:  sort_sel_kernel<512><<<B, 512, 0, stream>>>(timec, T, sel); break;
        case 256:  sort_sel_kernel<256><<<B, 256, 0, stream>>>(timec, T, sel); break;
        case 128:  sort_sel_kernel<128><<<B, 128, 0, stream>>>(timec, T, sel); break;
        default:   sort_sel_kernel<64><<<B, 64, 0, stream>>>(timec, T, sel); break;
      }
      unsigned short* p1; unsigned short* p2; int* nt;
      if ((lvl & 1) == 0) { p1 = zb1_A; p2 = zb2_A; nt = timeA; }
      else               { p1 = zb1_B; p2 = zb2_B; nt = timeB; }
      pool_kernel<<<dim3(T / 2, B), 320, 0, stream>>>(z1c, z2c, timec, sel, p1, p2, nt, T);
      z1c = p1; z2c = p2; timec = nt;
      T >>= 1;
    }
  }
}

// Round 4
// 397.491 us; speedup vs baseline: 4.1233x; 1.2575x over previous
//
#include <hip/hip_runtime.h>
#include <cstdint>
#include <cstddef>

#define D_DIM 320
#define NEGINF (-1e30f)
#define MAXS 16
#define WSROW 2048

typedef __attribute__((ext_vector_type(8))) short bf16x8_t;
typedef __attribute__((ext_vector_type(4))) float f32x4_t;

__device__ __forceinline__ float bf2f(unsigned short u) {
  union { unsigned int i; float f; } v; v.i = ((unsigned int)u) << 16; return v.f;
}
__device__ __forceinline__ unsigned short f2bf(float f) {
  union { float f; unsigned int i; } u; u.f = f;
  unsigned int b = u.i + 0x7FFFu + ((u.i >> 16) & 1u);
  return (unsigned short)(b >> 16);
}

__device__ __forceinline__ const unsigned short* zrowb(
    const unsigned short* __restrict__ z1, const unsigned short* __restrict__ z2,
    int b, int T, int r) {
  return (r < T) ? (z1 + ((size_t)b * T + r) * D_DIM)
                 : (z2 + ((size_t)b * T + (r - T)) * D_DIM);
}

#define GLOAD_LDS16(SRC, DST)                                                   \
  __builtin_amdgcn_global_load_lds(                                             \
      (const __attribute__((address_space(1))) void*)(SRC),                     \
      (__attribute__((address_space(3))) void*)(DST), 16, 0, 0)

// ---------------- fp32 -> bf16 convert (both arrays) + zero out ----------------
__global__ void convert_kernel(const float* __restrict__ i1, const float* __restrict__ i2,
                               unsigned short* __restrict__ o1, unsigned short* __restrict__ o2,
                               int n4, float* __restrict__ out, int outn) {
  int i = blockIdx.x * blockDim.x + threadIdx.x;
  if (i < outn) out[i] = 0.f;
  int stride = gridDim.x * blockDim.x;
  for (int j = i; j < n4; j += stride) {
    float4 v = ((const float4*)i1)[j];
    ushort4 r;
    r.x = f2bf(v.x); r.y = f2bf(v.y); r.z = f2bf(v.z); r.w = f2bf(v.w);
    ((ushort4*)o1)[j] = r;
    float4 u = ((const float4*)i2)[j];
    ushort4 q;
    q.x = f2bf(u.x); q.y = f2bf(u.y); q.z = f2bf(u.z); q.w = f2bf(u.w);
    ((ushort4*)o2)[j] = q;
  }
}

// ---------------- all-levels sort + selection + time chain, one launch --------
// sel/time chain is independent of z; one block per b, levels serial in LDS.
__global__ __launch_bounds__(1024) void sortall_kernel(
    const int* __restrict__ time0, int* __restrict__ sel_all) {
  int b = blockIdx.x;
  int tid = threadIdx.x;
  __shared__ int tcur[1024];
  __shared__ unsigned long long keys[1024];
  __shared__ int pfx[1024];
  __shared__ int tnew[512];

  tcur[tid] = time0[b * 1024 + tid];
  __syncthreads();

  int off = 0;
  for (int T = 1024; T >= 2; T >>= 1) {
    int n = T - 1, half = T >> 1;
    if (tid < T) {
      unsigned long long key = ~0ULL;
      if (tid < n) {
        unsigned d = (unsigned)(tcur[tid + 1] - tcur[tid]);
        key = ((unsigned long long)d << 10) | (unsigned)tid;
      }
      keys[tid] = key;
    }
    __syncthreads();
    for (int size = 2; size <= T; size <<= 1) {
      for (int stride = size >> 1; stride > 0; stride >>= 1) {
        if (tid < T) {
          int partner = tid ^ stride;
          if (partner > tid) {
            unsigned long long a = keys[tid], c = keys[partner];
            bool asc = (tid & size) == 0;
            if ((a > c) == asc) { keys[tid] = c; keys[partner] = a; }
          }
        }
        __syncthreads();
      }
    }
    int p = (tid < T) ? (int)(keys[tid] & 1023ULL) : 0;
    int mask = (tid < n && p < half) ? 1 : 0;
    if (tid < T) pfx[tid] = mask;
    __syncthreads();
    for (int o = 1; o < T; o <<= 1) {
      int t = 0;
      if (tid < T && tid >= o) t = pfx[tid - o];
      __syncthreads();
      if (tid < T) pfx[tid] += t;
      __syncthreads();
    }
    if (mask) {
      int rank = pfx[tid] - 1;
      sel_all[off + b * half + rank] = tid;
      tnew[rank] = (tcur[tid] + tcur[tid + 1]) >> 1;
    }
    __syncthreads();
    if (tid < half) tcur[tid] = tnew[tid];
    off += 8 * half;
    __syncthreads();
  }
}

// ---------------- temporal loss: one 128x128 tile per block ----------------
// 256 threads = 4 waves as 2(row)x2(col); wave tile 64x64; K dbuf BK=32.
// LDS 32KB -> 4 blocks/CU. Partial (m,s) per 128-col segment to workspace.
// Grid 1-D = 8*S*RB; bijective XCD swizzle -> each XCD owns one batch b
// (level data <=1.31MB, L2-resident).
__global__ __launch_bounds__(256, 4) void temporal_mfma_kernel(
    const unsigned short* __restrict__ z1, const unsigned short* __restrict__ z2,
    int T, int S, int RB, float* __restrict__ wsm, float* __restrict__ wss) {
  int N = 2 * T;
  int nwg = 8 * S * RB;
  int lid = blockIdx.x;
  int nid = (lid % 8) * (nwg / 8) + lid / 8;  // same-XCD -> contiguous nid
  int TPB = S * RB;
  int b = nid / TPB;
  int r = nid % TPB;
  int sgb = (S < 4) ? S : 4;
  int rbb = (RB < 4) ? RB : 4;
  int ic = sgb * rbb;
  int ci = r / ic, ii = r % ic;
  int ncx = S / sgb;
  int cx = ci % ncx, cy = ci / ncx;
  int sg = cx * sgb + ii % sgb;
  int rb = cy * rbb + ii / sgb;
  int row0 = rb * 128, col0 = sg * 128;

  int tid = threadIdx.x;
  int w = tid >> 6, lane = tid & 63;
  int lq = lane >> 4, lr = lane & 15;
  int wr = w >> 1, wc = w & 1;

  // [buf][ab][plane 4][row 128][8 bf16]
  __shared__ __align__(16) unsigned short lds[2 * 2 * 4 * 128 * 8];
  __shared__ float mS[2][128], sS[2][128];

  auto stage = [&](int k, int buf) {
    int kp = k * 4;
#pragma unroll
    for (int i = 0; i < 2; ++i) {
      int h = i * 64;
      {  // A: plane w, rows h..h+63
        int gr = row0 + h + lane;
        if (gr > N - 1) gr = N - 1;
        GLOAD_LDS16(zrowb(z1, z2, b, T, gr) + (kp + w) * 8,
                    &lds[(((buf * 2 + 0) * 4 + w) * 128 + h + lane) * 8]);
      }
      {  // B: plane w, cols h..h+63
        int gc = col0 + h + lane;
        if (gc > N - 1) gc = N - 1;
        GLOAD_LDS16(zrowb(z1, z2, b, T, gc) + (kp + w) * 8,
                    &lds[(((buf * 2 + 1) * 4 + w) * 128 + h + lane) * 8]);
      }
    }
  };

  f32x4_t acc[4][4];
#pragma unroll
  for (int at = 0; at < 4; ++at)
#pragma unroll
    for (int ct = 0; ct < 4; ++ct) acc[at][ct] = (f32x4_t)(0.f);

  stage(0, 0);
  __syncthreads();

  for (int k = 0; k < 10; ++k) {
    int buf = k & 1;
    if (k < 9) stage(k + 1, buf ^ 1);
    bf16x8_t af[4];
#pragma unroll
    for (int at = 0; at < 4; ++at)
      af[at] = *(const bf16x8_t*)&lds[(((buf * 2 + 0) * 4 + lq) * 128 + wr * 64 + at * 16 + lr) * 8];
#pragma unroll
    for (int ct = 0; ct < 4; ++ct) {
      bf16x8_t bf = *(const bf16x8_t*)&lds[(((buf * 2 + 1) * 4 + lq) * 128 + wc * 64 + ct * 16 + lr) * 8];
#pragma unroll
      for (int at = 0; at < 4; ++at)
        acc[at][ct] = __builtin_amdgcn_mfma_f32_16x16x32_bf16(af[at], bf, acc[at][ct], 0, 0, 0);
    }
    __syncthreads();
  }

  // ---- LSE over this block's 128 cols, butterfly over lr, partial to ws ----
#pragma unroll
  for (int at = 0; at < 4; ++at) {
#pragma unroll
    for (int rg = 0; rg < 4; ++rg) {
      int rloc = wr * 64 + at * 16 + lq * 4 + rg;
      int rglob = row0 + rloc;
      float v[4];
      float vmax = NEGINF;
#pragma unroll
      for (int ct = 0; ct < 4; ++ct) {
        int cg = col0 + wc * 64 + ct * 16 + lr;
        v[ct] = (cg < N && cg != rglob) ? acc[at][ct][rg] : NEGINF;
        vmax = fmaxf(vmax, v[ct]);
      }
      float sv = __expf(v[0] - vmax) + __expf(v[1] - vmax) +
                 __expf(v[2] - vmax) + __expf(v[3] - vmax);
      float m = vmax;
#pragma unroll
      for (int o = 1; o < 16; o <<= 1) {
        float m2 = __shfl_xor(m, o);
        float s2 = __shfl_xor(sv, o);
        float mN = fmaxf(m, m2);
        sv = sv * __expf(m - mN) + s2 * __expf(m2 - mN);
        m = mN;
      }
      if (lr == 0) { mS[wc][rloc] = m; sS[wc][rloc] = sv; }
    }
  }
  __syncthreads();

  if (tid < 128) {
    int rglob = row0 + tid;
    if (rglob < N) {
      float m0 = mS[0][tid], m1 = mS[1][tid];
      float m = fmaxf(m0, m1);
      float sv = sS[0][tid] * __expf(m0 - m) + sS[1][tid] * __expf(m1 - m);
      size_t idx = (size_t)(b * MAXS + sg) * WSROW + rglob;
      wsm[idx] = m;
      wss[idx] = sv;
    }
  }
}

// ---------------- fused epilogue: instance(level l) + combine(level l-1) -----
__global__ __launch_bounds__(256) void epi_kernel(
    const unsigned short* __restrict__ z1, const unsigned short* __restrict__ z2,
    int T, float scale,
    const unsigned short* __restrict__ pz1, const unsigned short* __restrict__ pz2,
    int Tprev, int Sprev, float scale_prev,
    const float* __restrict__ wsm, const float* __restrict__ wss,
    int do_comb, float* __restrict__ out) {
  int bx = blockIdx.x;
  int tid = threadIdx.x;

  if (bx < T) {
    // ---------- instance loss at time t = bx ----------
    int t = bx;
    __shared__ unsigned short Zs[16][328];
    __shared__ float Ss[16][17];
    __shared__ float Ls[16];
    for (int c = tid; c < 640; c += 256) {
      int i = c / 40, ko = c % 40;
      const unsigned short* p = (i < 8) ? (z1 + ((size_t)i * T + t) * D_DIM)
                                        : (z2 + ((size_t)(i - 8) * T + t) * D_DIM);
      *(bf16x8_t*)&Zs[i][ko * 8] = *(const bf16x8_t*)(p + ko * 8);
    }
    __syncthreads();

    int i = tid >> 4, j = tid & 15;
    float dot = 0.f;
    for (int k = 0; k < 40; ++k) {
      bf16x8_t a = *(const bf16x8_t*)&Zs[i][k * 8];
      bf16x8_t bb = *(const bf16x8_t*)&Zs[j][k * 8];
#pragma unroll
      for (int e = 0; e < 8; ++e)
        dot += bf2f((unsigned short)a[e]) * bf2f((unsigned short)bb[e]);
    }
    Ss[i][j] = dot;
    __syncthreads();

    if (tid < 16) {
      int rr = tid;
      float m = NEGINF;
      for (int c = 0; c < 16; ++c) if (c != rr) m = fmaxf(m, Ss[rr][c]);
      float s = 0.f;
      for (int c = 0; c < 16; ++c) if (c != rr) s += __expf(Ss[rr][c] - m);
      int pos = (rr < 8) ? rr + 8 : rr - 8;
      Ls[rr] = m + logf(s) - Ss[rr][pos];
    }
    __syncthreads();
    if (tid == 0) {
      float sum = 0.f;
      for (int rr = 0; rr < 16; ++rr) sum += Ls[rr];
      atomicAdd(out, sum * scale);
    }
  } else if (do_comb) {
    // ---------- combine partials of previous level's temporal ----------
    int Np = 2 * Tprev;
    int nc = (Np + 255) >> 8;
    int cj = bx - T;
    int b = cj / nc, rbk = cj % nc;
    int r = rbk * 256 + tid;
    float loss = 0.f;
    if (r < Np) {
      float m = NEGINF;
      for (int s = 0; s < Sprev; ++s)
        m = fmaxf(m, wsm[(size_t)(b * MAXS + s) * WSROW + r]);
      float sv = 0.f;
      for (int s = 0; s < Sprev; ++s) {
        size_t idx = (size_t)(b * MAXS + s) * WSROW + r;
        sv += wss[idx] * __expf(wsm[idx] - m);
      }
      int pos = (r < Tprev) ? r + Tprev : r - Tprev;
      const bf16x8_t* za = (const bf16x8_t*)zrowb(pz1, pz2, b, Tprev, r);
      const bf16x8_t* zp = (const bf16x8_t*)zrowb(pz1, pz2, b, Tprev, pos);
      float dot = 0.f;
      for (int k = 0; k < D_DIM / 8; ++k) {
        bf16x8_t a = za[k], p = zp[k];
#pragma unroll
        for (int e = 0; e < 8; ++e)
          dot += bf2f((unsigned short)a[e]) * bf2f((unsigned short)p[e]);
      }
      loss = m + logf(sv) - dot;
    }
    float v = loss;
#pragma unroll
    for (int o = 1; o < 64; o <<= 1) v += __shfl_xor(v, o);
    __shared__ float part[4];
    int w = tid >> 6;
    if ((tid & 63) == 0) part[w] = v;
    __syncthreads();
    if (tid == 0)
      atomicAdd(out, (part[0] + part[1] + part[2] + part[3]) * scale_prev);
  }
}

// ---------------- pool: max of adjacent rows, gathered at sel (bf16x8) -------
__global__ void pool_kernel(const unsigned short* __restrict__ z1,
                            const unsigned short* __restrict__ z2,
                            const int* __restrict__ sel,
                            unsigned short* __restrict__ o1,
                            unsigned short* __restrict__ o2, int T) {
  int half = T >> 1;
  int total = 8 * half * 40;
  for (int cid = blockIdx.x * blockDim.x + threadIdx.x; cid < total;
       cid += gridDim.x * blockDim.x) {
    int c = cid % 40;
    int j = (cid / 40) % half;
    int b = cid / (40 * half);
    int k = sel[b * half + j];
    size_t src = ((size_t)b * T + k) * D_DIM + c * 8;
    size_t dst = ((size_t)b * half + j) * D_DIM + c * 8;
    {
      bf16x8_t a = *(const bf16x8_t*)(z1 + src);
      bf16x8_t bb = *(const bf16x8_t*)(z1 + src + D_DIM);
      bf16x8_t rv;
#pragma unroll
      for (int e = 0; e < 8; ++e)
        rv[e] = (bf2f((unsigned short)a[e]) >= bf2f((unsigned short)bb[e])) ? a[e] : bb[e];
      *(bf16x8_t*)(o1 + dst) = rv;
    }
    {
      bf16x8_t a = *(const bf16x8_t*)(z2 + src);
      bf16x8_t bb = *(const bf16x8_t*)(z2 + src + D_DIM);
      bf16x8_t rv;
#pragma unroll
      for (int e = 0; e < 8; ++e)
        rv[e] = (bf2f((unsigned short)a[e]) >= bf2f((unsigned short)bb[e])) ? a[e] : bb[e];
      *(bf16x8_t*)(o2 + dst) = rv;
    }
  }
}

extern "C" void kernel_launch(void* const* d_in, const int* in_sizes, int n_in,
                              void* d_out, int out_size, void* d_ws, size_t ws_size,
                              hipStream_t stream) {
  const float* z1_in = (const float*)d_in[0];
  const float* z2_in = (const float*)d_in[1];
  const int* time_in = (const int*)d_in[2];
  float* out = (float*)d_out;
  const int B = 8;

  // workspace carve (bf16): level0 (1024), ping A (512), ping B (256)
  char* w = (char*)d_ws;
  size_t n0 = (size_t)B * 1024 * D_DIM;
  size_t nA = (size_t)B * 512 * D_DIM;
  size_t nB = (size_t)B * 256 * D_DIM;
  unsigned short* zb1_0 = (unsigned short*)w; w += n0 * 2;
  unsigned short* zb2_0 = (unsigned short*)w; w += n0 * 2;
  unsigned short* zb1_A = (unsigned short*)w; w += nA * 2;
  unsigned short* zb2_A = (unsigned short*)w; w += nA * 2;
  unsigned short* zb1_B = (unsigned short*)w; w += nB * 2;
  unsigned short* zb2_B = (unsigned short*)w; w += nB * 2;
  int* sel_all = (int*)w; w += (size_t)B * 1024 * sizeof(int);
  float* wsm = (float*)w; w += (size_t)B * MAXS * WSROW * sizeof(float);
  float* wss = (float*)w; w += (size_t)B * MAXS * WSROW * sizeof(float);

  convert_kernel<<<2048, 256, 0, stream>>>(z1_in, z2_in, zb1_0, zb2_0,
                                           (int)(n0 / 4), out, out_size);
  sortall_kernel<<<B, 1024, 0, stream>>>(time_in, sel_all);

  const unsigned short* z1c = zb1_0;
  const unsigned short* z2c = zb2_0;
  const unsigned short* z1p = zb1_0;
  const unsigned short* z2p = zb2_0;
  int Tprev = 0, Sprev = 1;
  float scale_prev = 0.f;
  int selOff = 0;
  int T = 1024;
  for (int lvl = 0; lvl < 11; ++lvl) {
    float scale = 1.0f / (352.0f * (float)T);  // 0.5/(2*B*T)/11
    int do_comb = (lvl > 0) ? 1 : 0;
    int combBlocks = do_comb ? B * (((2 * Tprev) + 255) >> 8) : 0;
    epi_kernel<<<T + combBlocks, 256, 0, stream>>>(
        z1c, z2c, T, scale, z1p, z2p, Tprev, Sprev, scale_prev, wsm, wss,
        do_comb, out);

    if (T > 1) {
      int N = 2 * T;
      int S = (N >= 128) ? N / 128 : 1;
      int RB = S;
      temporal_mfma_kernel<<<8 * S * RB, 256, 0, stream>>>(z1c, z2c, T, S, RB,
                                                           wsm, wss);
      // pool into next level buffer
      unsigned short* p1;
      unsigned short* p2;
      if ((lvl & 1) == 0) { p1 = zb1_A; p2 = zb2_A; }
      else                { p1 = zb1_B; p2 = zb2_B; }
      int half = T >> 1;
      int total = B * half * 40;
      int pgrid = (total + 255) / 256;
      if (pgrid > 2048) pgrid = 2048;
      pool_kernel<<<pgrid, 256, 0, stream>>>(z1c, z2c, sel_all + selOff, p1, p2, T);
      selOff += B * half;

      z1p = z1c; z2p = z2c;
      Tprev = T; Sprev = S; scale_prev = scale;
      z1c = p1; z2c = p2;
      T >>= 1;
    }
  }
}

// Round 5
// 266.185 us; speedup vs baseline: 6.1573x; 1.4933x over previous
//
#include <hip/hip_runtime.h>
#include <cstdint>
#include <cstddef>

#define D_DIM 320
#define NEGINF (-1e30f)
#define MAXS 16
#define WSROW 2048

typedef __attribute__((ext_vector_type(8))) short bf16x8_t;
typedef __attribute__((ext_vector_type(4))) float f32x4_t;

__device__ __forceinline__ float bf2f(unsigned short u) {
  union { unsigned int i; float f; } v; v.i = ((unsigned int)u) << 16; return v.f;
}
__device__ __forceinline__ unsigned short f2bf(float f) {
  union { float f; unsigned int i; } u; u.f = f;
  unsigned int b = u.i + 0x7FFFu + ((u.i >> 16) & 1u);
  return (unsigned short)(b >> 16);
}

__device__ __forceinline__ const unsigned short* zrowb(
    const unsigned short* __restrict__ z1, const unsigned short* __restrict__ z2,
    int b, int T, int r) {
  return (r < T) ? (z1 + ((size_t)b * T + r) * D_DIM)
                 : (z2 + ((size_t)b * T + (r - T)) * D_DIM);
}

#define GLOAD_LDS16(SRC, DST)                                                   \
  __builtin_amdgcn_global_load_lds(                                             \
      (const __attribute__((address_space(1))) void*)(SRC),                     \
      (__attribute__((address_space(3))) void*)(DST), 16, 0, 0)

// ---------------- fp32 -> bf16 convert (both arrays) + zero out ----------------
__global__ void convert_kernel(const float* __restrict__ i1, const float* __restrict__ i2,
                               unsigned short* __restrict__ o1, unsigned short* __restrict__ o2,
                               int n4, float* __restrict__ out, int outn) {
  int i = blockIdx.x * blockDim.x + threadIdx.x;
  if (i < outn) out[i] = 0.f;
  int stride = gridDim.x * blockDim.x;
  for (int j = i; j < n4; j += stride) {
    float4 v = ((const float4*)i1)[j];
    ushort4 r;
    r.x = f2bf(v.x); r.y = f2bf(v.y); r.z = f2bf(v.z); r.w = f2bf(v.w);
    ((ushort4*)o1)[j] = r;
    float4 u = ((const float4*)i2)[j];
    ushort4 q;
    q.x = f2bf(u.x); q.y = f2bf(u.y); q.z = f2bf(u.z); q.w = f2bf(u.w);
    ((ushort4*)o2)[j] = q;
  }
}

// ---------------- all-levels sort + selection + time chain, one launch --------
__global__ __launch_bounds__(1024) void sortall_kernel(
    const int* __restrict__ time0, int* __restrict__ sel_all) {
  int b = blockIdx.x;
  int tid = threadIdx.x;
  __shared__ int tcur[1024];
  __shared__ unsigned long long keys[1024];
  __shared__ int pfx[1024];
  __shared__ int tnew[512];

  tcur[tid] = time0[b * 1024 + tid];
  __syncthreads();

  int off = 0;
  for (int T = 1024; T >= 2; T >>= 1) {
    int n = T - 1, half = T >> 1;
    if (tid < T) {
      unsigned long long key = ~0ULL;
      if (tid < n) {
        unsigned d = (unsigned)(tcur[tid + 1] - tcur[tid]);
        key = ((unsigned long long)d << 10) | (unsigned)tid;
      }
      keys[tid] = key;
    }
    __syncthreads();
    for (int size = 2; size <= T; size <<= 1) {
      for (int stride = size >> 1; stride > 0; stride >>= 1) {
        if (tid < T) {
          int partner = tid ^ stride;
          if (partner > tid) {
            unsigned long long a = keys[tid], c = keys[partner];
            bool asc = (tid & size) == 0;
            if ((a > c) == asc) { keys[tid] = c; keys[partner] = a; }
          }
        }
        __syncthreads();
      }
    }
    int p = (tid < T) ? (int)(keys[tid] & 1023ULL) : 0;
    int mask = (tid < n && p < half) ? 1 : 0;
    if (tid < T) pfx[tid] = mask;
    __syncthreads();
    for (int o = 1; o < T; o <<= 1) {
      int t = 0;
      if (tid < T && tid >= o) t = pfx[tid - o];
      __syncthreads();
      if (tid < T) pfx[tid] += t;
      __syncthreads();
    }
    if (mask) {
      int rank = pfx[tid] - 1;
      sel_all[off + b * half + rank] = tid;
      tnew[rank] = (tcur[tid] + tcur[tid + 1]) >> 1;
    }
    __syncthreads();
    if (tid < half) tcur[tid] = tnew[tid];
    off += 8 * half;
    __syncthreads();
  }
}

// ---------------- one kernel per level: temporal | instance | combine | pool --
// roles by blockIdx.x: [0,nT) temporal tiles, [nT,nT+T) instance (1/t),
// [.., +nC) combine prev level, [.., +nP) pool (grid-stride).
__global__ __launch_bounds__(256, 4) void level_kernel(
    const unsigned short* __restrict__ z1, const unsigned short* __restrict__ z2,
    int T, float scale, int S, int do_temporal,
    float* __restrict__ wsm, float* __restrict__ wss,
    const unsigned short* __restrict__ pz1, const unsigned short* __restrict__ pz2,
    int Tprev, int Sprev, float scale_prev,
    const float* __restrict__ pwsm, const float* __restrict__ pwss, int do_comb,
    const int* __restrict__ sel, unsigned short* __restrict__ o1,
    unsigned short* __restrict__ o2, int do_pool, int nP,
    float* __restrict__ out) {
  __shared__ __align__(16) unsigned char smem[36864];
  int bx = blockIdx.x;
  int tid = threadIdx.x;
  int nT = do_temporal ? 8 * S * S : 0;
  int nC = do_comb ? 8 * (((2 * Tprev) + 255) >> 8) : 0;

  if (bx < nT) {
    // ================= temporal: one 128x128 tile =================
    int N = 2 * T;
    int nid = (bx % 8) * (nT / 8) + bx / 8;  // XCD cluster -> contiguous tiles
    int TPB = S * S;
    int b = nid / TPB;
    int r = nid % TPB;
    int sgb = (S < 4) ? S : 4;
    int ic = sgb * sgb;
    int ci = r / ic, ii = r % ic;
    int ncx = S / sgb;
    int cx = ci % ncx, cy = ci / ncx;
    int sg = cx * sgb + ii % sgb;
    int rb = cy * sgb + ii / sgb;
    int row0 = rb * 128, col0 = sg * 128;

    int w = tid >> 6, lane = tid & 63;
    int lq = lane >> 4, lr = lane & 15;
    int wr = w >> 1, wc = w & 1;

    unsigned short* lds = (unsigned short*)smem;            // 32768 B
    float (*mS)[128] = (float(*)[128])(smem + 32768);       // 1024 B
    float (*sS)[128] = (float(*)[128])(smem + 33792);       // 1024 B

    auto stage = [&](int k, int buf) {
      int kp = k * 4;
#pragma unroll
      for (int i = 0; i < 2; ++i) {
        int h = i * 64;
        {
          int gr = row0 + h + lane;
          if (gr > N - 1) gr = N - 1;
          GLOAD_LDS16(zrowb(z1, z2, b, T, gr) + (kp + w) * 8,
                      &lds[(((buf * 2 + 0) * 4 + w) * 128 + h + lane) * 8]);
        }
        {
          int gc = col0 + h + lane;
          if (gc > N - 1) gc = N - 1;
          GLOAD_LDS16(zrowb(z1, z2, b, T, gc) + (kp + w) * 8,
                      &lds[(((buf * 2 + 1) * 4 + w) * 128 + h + lane) * 8]);
        }
      }
    };

    f32x4_t acc[4][4];
#pragma unroll
    for (int at = 0; at < 4; ++at)
#pragma unroll
      for (int ct = 0; ct < 4; ++ct) acc[at][ct] = (f32x4_t)(0.f);

    stage(0, 0);
    __syncthreads();

    for (int k = 0; k < 10; ++k) {
      int buf = k & 1;
      if (k < 9) stage(k + 1, buf ^ 1);
      bf16x8_t af[4];
#pragma unroll
      for (int at = 0; at < 4; ++at)
        af[at] = *(const bf16x8_t*)&lds[(((buf * 2 + 0) * 4 + lq) * 128 + wr * 64 + at * 16 + lr) * 8];
#pragma unroll
      for (int ct = 0; ct < 4; ++ct) {
        bf16x8_t bf = *(const bf16x8_t*)&lds[(((buf * 2 + 1) * 4 + lq) * 128 + wc * 64 + ct * 16 + lr) * 8];
#pragma unroll
        for (int at = 0; at < 4; ++at)
          acc[at][ct] = __builtin_amdgcn_mfma_f32_16x16x32_bf16(af[at], bf, acc[at][ct], 0, 0, 0);
      }
      __syncthreads();
    }

    // ---- two-pass LSE: max-butterfly (uniform m), then exp-sum butterfly ----
#pragma unroll
    for (int at = 0; at < 4; ++at) {
#pragma unroll
      for (int rg = 0; rg < 4; ++rg) {
        int rloc = wr * 64 + at * 16 + lq * 4 + rg;
        int rglob = row0 + rloc;
        float v[4];
#pragma unroll
        for (int ct = 0; ct < 4; ++ct) {
          int cg = col0 + wc * 64 + ct * 16 + lr;
          v[ct] = (cg < N && cg != rglob) ? acc[at][ct][rg] : NEGINF;
        }
        float m = fmaxf(fmaxf(v[0], v[1]), fmaxf(v[2], v[3]));
#pragma unroll
        for (int o = 1; o < 16; o <<= 1) m = fmaxf(m, __shfl_xor(m, o));
        float sv = __expf(v[0] - m) + __expf(v[1] - m) +
                   __expf(v[2] - m) + __expf(v[3] - m);
#pragma unroll
        for (int o = 1; o < 16; o <<= 1) sv += __shfl_xor(sv, o);
        if (lr == 0) { mS[wc][rloc] = m; sS[wc][rloc] = sv; }
      }
    }
    __syncthreads();

    if (tid < 128) {
      int rglob = row0 + tid;
      if (rglob < N) {
        float m0 = mS[0][tid], m1 = mS[1][tid];
        float m = fmaxf(m0, m1);
        float sv = sS[0][tid] * __expf(m0 - m) + sS[1][tid] * __expf(m1 - m);
        size_t idx = (size_t)(b * MAXS + sg) * WSROW + rglob;
        wsm[idx] = m;
        wss[idx] = sv;
      }
    }
  } else if (bx < nT + T) {
    // ================= instance loss at t = bx - nT =================
    int t = bx - nT;
    unsigned short (*Zs)[328] = (unsigned short(*)[328])smem;   // 10496 B
    float (*Ss)[17] = (float(*)[17])(smem + 10496);             // 1088 B
    float* Ls = (float*)(smem + 11584);
    for (int c = tid; c < 640; c += 256) {
      int i = c / 40, ko = c % 40;
      const unsigned short* p = (i < 8) ? (z1 + ((size_t)i * T + t) * D_DIM)
                                        : (z2 + ((size_t)(i - 8) * T + t) * D_DIM);
      *(bf16x8_t*)&Zs[i][ko * 8] = *(const bf16x8_t*)(p + ko * 8);
    }
    __syncthreads();

    int i = tid >> 4, j = tid & 15;
    float dot = 0.f;
    for (int k = 0; k < 40; ++k) {
      bf16x8_t a = *(const bf16x8_t*)&Zs[i][k * 8];
      bf16x8_t bb = *(const bf16x8_t*)&Zs[j][k * 8];
#pragma unroll
      for (int e = 0; e < 8; ++e)
        dot += bf2f((unsigned short)a[e]) * bf2f((unsigned short)bb[e]);
    }
    Ss[i][j] = dot;
    __syncthreads();

    if (tid < 16) {
      int rr = tid;
      float m = NEGINF;
      for (int c = 0; c < 16; ++c) if (c != rr) m = fmaxf(m, Ss[rr][c]);
      float s = 0.f;
      for (int c = 0; c < 16; ++c) if (c != rr) s += __expf(Ss[rr][c] - m);
      int pos = (rr < 8) ? rr + 8 : rr - 8;
      Ls[rr] = m + logf(s) - Ss[rr][pos];
    }
    __syncthreads();
    if (tid == 0) {
      float sum = 0.f;
      for (int rr = 0; rr < 16; ++rr) sum += Ls[rr];
      atomicAdd(out, sum * scale);
    }
  } else if (bx < nT + T + nC) {
    // ================= combine prev level's temporal partials =================
    int Np = 2 * Tprev;
    int nc = (Np + 255) >> 8;
    int cj = bx - nT - T;
    int b = cj / nc, rbk = cj % nc;
    int r = rbk * 256 + tid;
    float loss = 0.f;
    if (r < Np) {
      float m = NEGINF;
      for (int s = 0; s < Sprev; ++s)
        m = fmaxf(m, pwsm[(size_t)(b * MAXS + s) * WSROW + r]);
      float sv = 0.f;
      for (int s = 0; s < Sprev; ++s) {
        size_t idx = (size_t)(b * MAXS + s) * WSROW + r;
        sv += pwss[idx] * __expf(pwsm[idx] - m);
      }
      int pos = (r < Tprev) ? r + Tprev : r - Tprev;
      const bf16x8_t* za = (const bf16x8_t*)zrowb(pz1, pz2, b, Tprev, r);
      const bf16x8_t* zp = (const bf16x8_t*)zrowb(pz1, pz2, b, Tprev, pos);
      float dot = 0.f;
      for (int k = 0; k < D_DIM / 8; ++k) {
        bf16x8_t a = za[k], p = zp[k];
#pragma unroll
        for (int e = 0; e < 8; ++e)
          dot += bf2f((unsigned short)a[e]) * bf2f((unsigned short)p[e]);
      }
      loss = m + logf(sv) - dot;
    }
    float v = loss;
#pragma unroll
    for (int o = 1; o < 64; o <<= 1) v += __shfl_xor(v, o);
    float* part = (float*)smem;
    int w = tid >> 6;
    if ((tid & 63) == 0) part[w] = v;
    __syncthreads();
    if (tid == 0)
      atomicAdd(out, (part[0] + part[1] + part[2] + part[3]) * scale_prev);
  } else if (do_pool) {
    // ================= pool (max adjacent) gathered at sel =================
    int pb = bx - nT - T - nC;
    int half = T >> 1;
    int total = 8 * half * 40;
    for (int cid = pb * 256 + tid; cid < total; cid += nP * 256) {
      int c = cid % 40;
      int j = (cid / 40) % half;
      int b = cid / (40 * half);
      int k = sel[b * half + j];
      size_t src = ((size_t)b * T + k) * D_DIM + c * 8;
      size_t dst = ((size_t)b * half + j) * D_DIM + c * 8;
      {
        bf16x8_t a = *(const bf16x8_t*)(z1 + src);
        bf16x8_t bb = *(const bf16x8_t*)(z1 + src + D_DIM);
        bf16x8_t rv;
#pragma unroll
        for (int e = 0; e < 8; ++e)
          rv[e] = (bf2f((unsigned short)a[e]) >= bf2f((unsigned short)bb[e])) ? a[e] : bb[e];
        *(bf16x8_t*)(o1 + dst) = rv;
      }
      {
        bf16x8_t a = *(const bf16x8_t*)(z2 + src);
        bf16x8_t bb = *(const bf16x8_t*)(z2 + src + D_DIM);
        bf16x8_t rv;
#pragma unroll
        for (int e = 0; e < 8; ++e)
          rv[e] = (bf2f((unsigned short)a[e]) >= bf2f((unsigned short)bb[e])) ? a[e] : bb[e];
        *(bf16x8_t*)(o2 + dst) = rv;
      }
    }
  }
}

extern "C" void kernel_launch(void* const* d_in, const int* in_sizes, int n_in,
                              void* d_out, int out_size, void* d_ws, size_t ws_size,
                              hipStream_t stream) {
  const float* z1_in = (const float*)d_in[0];
  const float* z2_in = (const float*)d_in[1];
  const int* time_in = (const int*)d_in[2];
  float* out = (float*)d_out;
  const int B = 8;

  // workspace carve: level0 bf16 (1024), ring of 3 (512-sized), sel, partials x2
  char* w = (char*)d_ws;
  size_t n0 = (size_t)B * 1024 * D_DIM;
  size_t nR = (size_t)B * 512 * D_DIM;
  unsigned short* zb1_0 = (unsigned short*)w; w += n0 * 2;
  unsigned short* zb2_0 = (unsigned short*)w; w += n0 * 2;
  unsigned short* ring1[3];
  unsigned short* ring2[3];
  for (int i = 0; i < 3; ++i) {
    ring1[i] = (unsigned short*)w; w += nR * 2;
    ring2[i] = (unsigned short*)w; w += nR * 2;
  }
  int* sel_all = (int*)w; w += (size_t)B * 1024 * sizeof(int);
  float* wsmP[2];
  float* wssP[2];
  for (int i = 0; i < 2; ++i) {
    wsmP[i] = (float*)w; w += (size_t)B * MAXS * WSROW * sizeof(float);
    wssP[i] = (float*)w; w += (size_t)B * MAXS * WSROW * sizeof(float);
  }

  convert_kernel<<<2048, 256, 0, stream>>>(z1_in, z2_in, zb1_0, zb2_0,
                                           (int)(n0 / 4), out, out_size);
  sortall_kernel<<<B, 1024, 0, stream>>>(time_in, sel_all);

  const unsigned short* z1c = zb1_0;
  const unsigned short* z2c = zb2_0;
  const unsigned short* z1p = zb1_0;
  const unsigned short* z2p = zb2_0;
  int Tprev = 0, Sprev = 1;
  float scale_prev = 0.f;
  int selOff = 0;
  int T = 1024;
  for (int lvl = 0; lvl < 11; ++lvl) {
    float scale = 1.0f / (352.0f * (float)T);  // 0.5/(2*B*T)/11
    int do_temporal = (T > 1) ? 1 : 0;
    int do_pool = (T > 1) ? 1 : 0;
    int do_comb = (lvl > 0) ? 1 : 0;
    int N = 2 * T;
    int S = (N >= 128) ? N / 128 : 1;
    int nT = do_temporal ? 8 * S * S : 0;
    int nC = do_comb ? B * ((2 * Tprev + 255) >> 8) : 0;
    int nP = 0;
    if (do_pool) {
      int total = B * (T >> 1) * 40;
      nP = (total + 255) / 256;
      if (nP > 512) nP = 512;
    }
    unsigned short* p1 = do_pool ? ring1[lvl % 3] : nullptr;
    unsigned short* p2 = do_pool ? ring2[lvl % 3] : nullptr;

    level_kernel<<<nT + T + nC + nP, 256, 0, stream>>>(
        z1c, z2c, T, scale, S, do_temporal,
        wsmP[lvl & 1], wssP[lvl & 1],
        z1p, z2p, Tprev, Sprev, scale_prev,
        wsmP[(lvl + 1) & 1], wssP[(lvl + 1) & 1], do_comb,
        sel_all + selOff, p1, p2, do_pool, nP, out);

    if (T > 1) {
      selOff += B * (T >> 1);
      z1p = z1c; z2p = z2c;
      Tprev = T; Sprev = S; scale_prev = scale;
      z1c = p1; z2c = p2;
      T >>= 1;
    }
  }
}

// Round 6
// 248.267 us; speedup vs baseline: 6.6017x; 1.0722x over previous
//
#include <hip/hip_runtime.h>
#include <cstdint>
#include <cstddef>

#define D_DIM 320
#define NEGINF (-1e30f)

typedef __attribute__((ext_vector_type(8))) short bf16x8_t;
typedef __attribute__((ext_vector_type(4))) float f32x4_t;

struct Tab {
  int T[11], S[11], zoff[11], wsoff[11];
  int tileStart[12], instStart[12], rstart[11];
  float scale[11];
  int totTemp, totInst, totr;
};

__device__ __forceinline__ float bf2f(unsigned short u) {
  union { unsigned int i; float f; } v; v.i = ((unsigned int)u) << 16; return v.f;
}
__device__ __forceinline__ unsigned short f2bf(float f) {
  union { float f; unsigned int i; } u; u.f = f;
  unsigned int b = u.i + 0x7FFFu + ((u.i >> 16) & 1u);
  return (unsigned short)(b >> 16);
}

__device__ __forceinline__ const unsigned short* zrowb(
    const unsigned short* __restrict__ z1, const unsigned short* __restrict__ z2,
    int b, int T, int r) {
  return (r < T) ? (z1 + ((size_t)b * T + r) * D_DIM)
                 : (z2 + ((size_t)b * T + (r - T)) * D_DIM);
}

#define GLOAD_LDS16(SRC, DST)                                                   \
  __builtin_amdgcn_global_load_lds(                                             \
      (const __attribute__((address_space(1))) void*)(SRC),                     \
      (__attribute__((address_space(3))) void*)(DST), 16, 0, 0)

// ---------------- fp32 -> bf16 convert (both arrays) + zero out ----------------
__global__ void convert_kernel(const float* __restrict__ i1, const float* __restrict__ i2,
                               unsigned short* __restrict__ o1, unsigned short* __restrict__ o2,
                               int n4, float* __restrict__ out, int outn) {
  int i = blockIdx.x * blockDim.x + threadIdx.x;
  if (i < outn) out[i] = 0.f;
  int stride = gridDim.x * blockDim.x;
  for (int j = i; j < n4; j += stride) {
    float4 v = ((const float4*)i1)[j];
    ushort4 r;
    r.x = f2bf(v.x); r.y = f2bf(v.y); r.z = f2bf(v.z); r.w = f2bf(v.w);
    ((ushort4*)o1)[j] = r;
    float4 u = ((const float4*)i2)[j];
    ushort4 q;
    q.x = f2bf(u.x); q.y = f2bf(u.y); q.z = f2bf(u.z); q.w = f2bf(u.w);
    ((ushort4*)o2)[j] = q;
  }
}

// ---------------- all-levels sort + selection + time chain, one launch --------
// bitonic: stride<64 in-register shfl (no barrier); stride>=64 via LDS.
// selection rank via ballot+popc (2 barriers) instead of Hillis-Steele scan.
__global__ __launch_bounds__(1024) void sortall_kernel(
    const int* __restrict__ time0, int* __restrict__ sel_all) {
  int b = blockIdx.x;
  int tid = threadIdx.x;
  int lane = tid & 63, wid = tid >> 6;
  __shared__ int tcur[1024];
  __shared__ unsigned long long kl[1024];
  __shared__ int wcnt[16];
  __shared__ int tnew[512];

  tcur[tid] = time0[b * 1024 + tid];
  __syncthreads();

  int off = 0;
  for (int T = 1024; T >= 2; T >>= 1) {
    int n = T - 1, half = T >> 1;
    unsigned long long key = ~0ULL;
    if (tid < n) {
      unsigned d = (unsigned)(tcur[tid + 1] - tcur[tid]);
      key = ((unsigned long long)d << 10) | (unsigned)tid;
    }
    for (int size = 2; size <= T; size <<= 1) {
      bool up = ((tid & size) == 0);
      for (int stride = size >> 1; stride > 0; stride >>= 1) {
        bool lower = ((tid & stride) == 0);
        bool takemin = (lower == up);
        if (stride >= 64) {
          if (tid < T) kl[tid] = key;
          __syncthreads();
          if (tid < T) {
            unsigned long long pk = kl[tid ^ stride];
            unsigned long long mn = key < pk ? key : pk;
            unsigned long long mx = key < pk ? pk : key;
            key = takemin ? mn : mx;
          }
          __syncthreads();
        } else {
          unsigned klo = (unsigned)key, khi = (unsigned)(key >> 32);
          unsigned plo = __shfl_xor((int)klo, stride);
          unsigned phi = __shfl_xor((int)khi, stride);
          unsigned long long pk = ((unsigned long long)phi << 32) | plo;
          unsigned long long mn = key < pk ? key : pk;
          unsigned long long mx = key < pk ? pk : key;
          key = takemin ? mn : mx;
        }
      }
    }
    int p = (int)(key & 1023ULL);
    bool mask = (tid < n) && (p < half);
    unsigned long long bal = __ballot(mask);
    int rw = __popcll(bal & ((1ull << lane) - 1ull));
    if (lane == 0) wcnt[wid] = (int)__popcll(bal);
    __syncthreads();
    int pre = 0;
    for (int i = 0; i < wid; ++i) pre += wcnt[i];
    if (mask) {
      int rank = pre + rw;
      sel_all[off + b * half + rank] = tid;
      tnew[rank] = (tcur[tid] + tcur[tid + 1]) >> 1;
    }
    __syncthreads();
    if (tid < half) tcur[tid] = tnew[tid];
    off += 8 * half;
    __syncthreads();
  }
}

// ---------------- pool chain: all 10 levels, one launch ----------------
// blocks = 8 b x 2 z-array x 5 d-chunks (64 bf16). Chain serial per block;
// global RAW guarded by threadfence+syncthreads (same block only).
__global__ __launch_bounds__(256) void poolchain_kernel(
    const int* __restrict__ sel_all,
    unsigned short* __restrict__ z1, unsigned short* __restrict__ z2) {
  int bx = blockIdx.x;
  int tid = threadIdx.x;
  int chunk = bx % 5;
  int zi = (bx / 5) & 1;
  int b = bx / 10;
  unsigned short* z = (zi == 0) ? z1 : z2;

  int off = 0;
  int zo_cur = 0;
  for (int l = 0; l < 10; ++l) {
    int T = 1024 >> l, half = T >> 1;
    int zo_nxt = zo_cur + 8 * T * D_DIM;
    const int* selp = sel_all + off + b * half;
    for (int u = tid; u < half * 8; u += 256) {
      int j = u >> 3, c = u & 7;
      int k = selp[j];
      size_t src = (size_t)zo_cur + ((size_t)b * T + k) * D_DIM + chunk * 64 + c * 8;
      size_t dst = (size_t)zo_nxt + ((size_t)b * half + j) * D_DIM + chunk * 64 + c * 8;
      bf16x8_t a = *(const bf16x8_t*)(z + src);
      bf16x8_t bb = *(const bf16x8_t*)(z + src + D_DIM);
      bf16x8_t rv;
#pragma unroll
      for (int e = 0; e < 8; ++e)
        rv[e] = (bf2f((unsigned short)a[e]) >= bf2f((unsigned short)bb[e])) ? a[e] : bb[e];
      *(bf16x8_t*)(z + dst) = rv;
    }
    __threadfence();
    __syncthreads();
    off += 8 * half;
    zo_cur = zo_nxt;
  }
}

// ---------------- mega: ALL levels' temporal tiles + instance blocks ----------
__global__ __launch_bounds__(256, 4) void mega_kernel(
    const unsigned short* __restrict__ z1, const unsigned short* __restrict__ z2,
    float* __restrict__ wsm, float* __restrict__ wss,
    float* __restrict__ out, Tab tab) {
  __shared__ __align__(16) unsigned char smem[36864];
  int bx = blockIdx.x;
  int tid = threadIdx.x;

  if (bx < tab.totTemp) {
    // ================= temporal: one 128x128 tile =================
    int l = 0;
    while (bx >= tab.tileStart[l + 1]) ++l;
    int T = tab.T[l], S = tab.S[l];
    int N = 2 * T;
    const unsigned short* zz1 = z1 + tab.zoff[l];
    const unsigned short* zz2 = z2 + tab.zoff[l];
    float* wm = wsm + tab.wsoff[l];
    float* wv = wss + tab.wsoff[l];

    int local = bx - tab.tileStart[l];
    int nTl = 8 * S * S;
    int nid = (local % 8) * (nTl / 8) + local / 8;
    int TPB = S * S;
    int b = nid / TPB;
    int r = nid % TPB;
    int sgb = (S < 4) ? S : 4;
    int ic = sgb * sgb;
    int ci = r / ic, ii = r % ic;
    int ncx = S / sgb;
    int cx = ci % ncx, cy = ci / ncx;
    int sg = cx * sgb + ii % sgb;
    int rb = cy * sgb + ii / sgb;
    int row0 = rb * 128, col0 = sg * 128;

    int w = tid >> 6, lane = tid & 63;
    int lq = lane >> 4, lr = lane & 15;
    int wr = w >> 1, wc = w & 1;

    unsigned short* lds = (unsigned short*)smem;            // 32768 B
    float (*mS)[128] = (float(*)[128])(smem + 32768);
    float (*sS)[128] = (float(*)[128])(smem + 33792);

    auto stage = [&](int k, int buf) {
      int kp = k * 4;
#pragma unroll
      for (int i = 0; i < 2; ++i) {
        int h = i * 64;
        {
          int gr = row0 + h + lane;
          if (gr > N - 1) gr = N - 1;
          GLOAD_LDS16(zrowb(zz1, zz2, b, T, gr) + (kp + w) * 8,
                      &lds[(((buf * 2 + 0) * 4 + w) * 128 + h + lane) * 8]);
        }
        {
          int gc = col0 + h + lane;
          if (gc > N - 1) gc = N - 1;
          GLOAD_LDS16(zrowb(zz1, zz2, b, T, gc) + (kp + w) * 8,
                      &lds[(((buf * 2 + 1) * 4 + w) * 128 + h + lane) * 8]);
        }
      }
    };

    f32x4_t acc[4][4];
#pragma unroll
    for (int at = 0; at < 4; ++at)
#pragma unroll
      for (int ct = 0; ct < 4; ++ct) acc[at][ct] = (f32x4_t)(0.f);

    stage(0, 0);
    __syncthreads();

    for (int k = 0; k < 10; ++k) {
      int buf = k & 1;
      if (k < 9) stage(k + 1, buf ^ 1);
      bf16x8_t af[4];
#pragma unroll
      for (int at = 0; at < 4; ++at)
        af[at] = *(const bf16x8_t*)&lds[(((buf * 2 + 0) * 4 + lq) * 128 + wr * 64 + at * 16 + lr) * 8];
#pragma unroll
      for (int ct = 0; ct < 4; ++ct) {
        bf16x8_t bf = *(const bf16x8_t*)&lds[(((buf * 2 + 1) * 4 + lq) * 128 + wc * 64 + ct * 16 + lr) * 8];
#pragma unroll
        for (int at = 0; at < 4; ++at)
          acc[at][ct] = __builtin_amdgcn_mfma_f32_16x16x32_bf16(af[at], bf, acc[at][ct], 0, 0, 0);
      }
      __syncthreads();
    }

    // two-pass LSE over this block's 128 cols
#pragma unroll
    for (int at = 0; at < 4; ++at) {
#pragma unroll
      for (int rg = 0; rg < 4; ++rg) {
        int rloc = wr * 64 + at * 16 + lq * 4 + rg;
        int rglob = row0 + rloc;
        float v[4];
#pragma unroll
        for (int ct = 0; ct < 4; ++ct) {
          int cg = col0 + wc * 64 + ct * 16 + lr;
          v[ct] = (cg < N && cg != rglob) ? acc[at][ct][rg] : NEGINF;
        }
        float m = fmaxf(fmaxf(v[0], v[1]), fmaxf(v[2], v[3]));
#pragma unroll
        for (int o = 1; o < 16; o <<= 1) m = fmaxf(m, __shfl_xor(m, o));
        float sv = __expf(v[0] - m) + __expf(v[1] - m) +
                   __expf(v[2] - m) + __expf(v[3] - m);
#pragma unroll
        for (int o = 1; o < 16; o <<= 1) sv += __shfl_xor(sv, o);
        if (lr == 0) { mS[wc][rloc] = m; sS[wc][rloc] = sv; }
      }
    }
    __syncthreads();

    if (tid < 128) {
      int rglob = row0 + tid;
      if (rglob < N) {
        float m0 = mS[0][tid], m1 = mS[1][tid];
        float m = fmaxf(m0, m1);
        float sv = sS[0][tid] * __expf(m0 - m) + sS[1][tid] * __expf(m1 - m);
        int idx = (b * S + sg) * N + rglob;
        wm[idx] = m;
        wv[idx] = sv;
      }
    }
  } else {
    // ================= instance loss =================
    int ix = bx - tab.totTemp;
    int l = 0;
    while (ix >= tab.instStart[l + 1]) ++l;
    int t = ix - tab.instStart[l];
    int T = tab.T[l];
    const unsigned short* zz1 = z1 + tab.zoff[l];
    const unsigned short* zz2 = z2 + tab.zoff[l];
    float scale = tab.scale[l];

    unsigned short (*Zs)[328] = (unsigned short(*)[328])smem;
    float (*Ss)[17] = (float(*)[17])(smem + 10496);
    float* Ls = (float*)(smem + 11584);
    for (int c = tid; c < 640; c += 256) {
      int i = c / 40, ko = c % 40;
      const unsigned short* p = (i < 8) ? (zz1 + ((size_t)i * T + t) * D_DIM)
                                        : (zz2 + ((size_t)(i - 8) * T + t) * D_DIM);
      *(bf16x8_t*)&Zs[i][ko * 8] = *(const bf16x8_t*)(p + ko * 8);
    }
    __syncthreads();

    int i = tid >> 4, j = tid & 15;
    float dot = 0.f;
    for (int k = 0; k < 40; ++k) {
      bf16x8_t a = *(const bf16x8_t*)&Zs[i][k * 8];
      bf16x8_t bb = *(const bf16x8_t*)&Zs[j][k * 8];
#pragma unroll
      for (int e = 0; e < 8; ++e)
        dot += bf2f((unsigned short)a[e]) * bf2f((unsigned short)bb[e]);
    }
    Ss[i][j] = dot;
    __syncthreads();

    if (tid < 16) {
      int rr = tid;
      float m = NEGINF;
      for (int c = 0; c < 16; ++c) if (c != rr) m = fmaxf(m, Ss[rr][c]);
      float s = 0.f;
      for (int c = 0; c < 16; ++c) if (c != rr) s += __expf(Ss[rr][c] - m);
      int pos = (rr < 8) ? rr + 8 : rr - 8;
      Ls[rr] = m + logf(s) - Ss[rr][pos];
    }
    __syncthreads();
    if (tid == 0) {
      float sum = 0.f;
      for (int rr = 0; rr < 16; ++rr) sum += Ls[rr];
      atomicAdd(out, sum * scale);
    }
  }
}

// ---------------- combine all levels' temporal partials, one launch ----------
__global__ __launch_bounds__(256) void combine_kernel(
    const unsigned short* __restrict__ z1, const unsigned short* __restrict__ z2,
    const float* __restrict__ wsm, const float* __restrict__ wss,
    float* __restrict__ out, Tab tab) {
  int g = blockIdx.x * 256 + threadIdx.x;
  float loss = 0.f;
  if (g < tab.totr) {
    int l = 0;
    while (g >= tab.rstart[l + 1]) ++l;
    int row = g - tab.rstart[l];
    int T = tab.T[l], N = 2 * T, S = tab.S[l];
    int b = row / N, r = row % N;
    const float* wm = wsm + tab.wsoff[l];
    const float* wv = wss + tab.wsoff[l];
    float m = NEGINF;
    for (int s = 0; s < S; ++s) m = fmaxf(m, wm[(b * S + s) * N + r]);
    float sv = 0.f;
    for (int s = 0; s < S; ++s) {
      int idx = (b * S + s) * N + r;
      sv += wv[idx] * __expf(wm[idx] - m);
    }
    const unsigned short* zz1 = z1 + tab.zoff[l];
    const unsigned short* zz2 = z2 + tab.zoff[l];
    int pos = (r < T) ? r + T : r - T;
    const bf16x8_t* za = (const bf16x8_t*)zrowb(zz1, zz2, b, T, r);
    const bf16x8_t* zp = (const bf16x8_t*)zrowb(zz1, zz2, b, T, pos);
    float dot = 0.f;
    for (int k = 0; k < D_DIM / 8; ++k) {
      bf16x8_t a = za[k], p = zp[k];
#pragma unroll
      for (int e = 0; e < 8; ++e)
        dot += bf2f((unsigned short)a[e]) * bf2f((unsigned short)p[e]);
    }
    loss = (m + logf(sv) - dot) * tab.scale[l];
  }
  float v = loss;
#pragma unroll
  for (int o = 1; o < 64; o <<= 1) v += __shfl_xor(v, o);
  __shared__ float part[4];
  int w = threadIdx.x >> 6;
  if ((threadIdx.x & 63) == 0) part[w] = v;
  __syncthreads();
  if (threadIdx.x == 0)
    atomicAdd(out, part[0] + part[1] + part[2] + part[3]);
}

extern "C" void kernel_launch(void* const* d_in, const int* in_sizes, int n_in,
                              void* d_out, int out_size, void* d_ws, size_t ws_size,
                              hipStream_t stream) {
  const float* z1_in = (const float*)d_in[0];
  const float* z2_in = (const float*)d_in[1];
  const int* time_in = (const int*)d_in[2];
  float* out = (float*)d_out;

  // ---- build level tables ----
  Tab tab;
  int zo = 0, wso = 0, ts = 0, is = 0, rs = 0;
  for (int l = 0; l < 11; ++l) {
    int T = 1024 >> l, N = 2 * T;
    int S = (N >= 128) ? N / 128 : 1;
    tab.T[l] = T;
    tab.S[l] = S;
    tab.zoff[l] = zo;
    tab.scale[l] = 1.0f / (352.0f * (float)T);  // 0.5/(2*B*T)/11
    tab.tileStart[l] = ts;
    tab.instStart[l] = is;
    tab.wsoff[l] = (T > 1) ? wso : 0;
    if (l < 10) tab.rstart[l] = rs;
    if (T > 1) {
      ts += 8 * S * S;
      wso += 8 * S * N;
      rs += 8 * N;
    }
    is += T;
    zo += 8 * T * D_DIM;
  }
  tab.tileStart[11] = ts;
  tab.instStart[11] = is;
  tab.rstart[10] = rs;
  tab.totTemp = ts;
  tab.totInst = is;
  tab.totr = rs;

  // ---- workspace carve ----
  char* w = (char*)d_ws;
  unsigned short* z1s = (unsigned short*)w; w += (size_t)zo * 2;
  unsigned short* z2s = (unsigned short*)w; w += (size_t)zo * 2;
  int* sel_all = (int*)w; w += 8192 * sizeof(int);
  float* wsm = (float*)w; w += (size_t)wso * sizeof(float);
  float* wss = (float*)w; w += (size_t)wso * sizeof(float);

  int n0 = 8 * 1024 * D_DIM;
  convert_kernel<<<2048, 256, 0, stream>>>(z1_in, z2_in, z1s, z2s, n0 / 4,
                                           out, out_size);
  sortall_kernel<<<8, 1024, 0, stream>>>(time_in, sel_all);
  poolchain_kernel<<<80, 256, 0, stream>>>(sel_all, z1s, z2s);
  mega_kernel<<<ts + is, 256, 0, stream>>>(z1s, z2s, wsm, wss, out, tab);
  combine_kernel<<<(rs + 255) / 256, 256, 0, stream>>>(z1s, z2s, wsm, wss, out, tab);
}

// Round 7
// 179.886 us; speedup vs baseline: 9.1112x; 1.3801x over previous
//
#include <hip/hip_runtime.h>
#include <cstdint>
#include <cstddef>

#define D_DIM 320
#define NEGINF (-1e30f)

typedef __attribute__((ext_vector_type(8))) short bf16x8_t;
typedef __attribute__((ext_vector_type(4))) float f32x4_t;

struct Tab {
  int T[11], S[11], zoff[11], wsoff[11];
  int tileStart[12], instStart[12], rstart[11];
  float scale[11];
  int totTemp, totInst, totr;
};

__device__ __forceinline__ float bf2f(unsigned short u) {
  union { unsigned int i; float f; } v; v.i = ((unsigned int)u) << 16; return v.f;
}
__device__ __forceinline__ unsigned short f2bf(float f) {
  union { float f; unsigned int i; } u; u.f = f;
  unsigned int b = u.i + 0x7FFFu + ((u.i >> 16) & 1u);
  return (unsigned short)(b >> 16);
}

__device__ __forceinline__ const unsigned short* zrowb(
    const unsigned short* __restrict__ z1, const unsigned short* __restrict__ z2,
    int b, int T, int r) {
  return (r < T) ? (z1 + ((size_t)b * T + r) * D_DIM)
                 : (z2 + ((size_t)b * T + (r - T)) * D_DIM);
}

#define GLOAD_LDS16(SRC, DST)                                                   \
  __builtin_amdgcn_global_load_lds(                                             \
      (const __attribute__((address_space(1))) void*)(SRC),                     \
      (__attribute__((address_space(3))) void*)(DST), 16, 0, 0)

// ---------------- fp32 -> bf16 convert (both arrays) + zero out ----------------
__global__ void convert_kernel(const float* __restrict__ i1, const float* __restrict__ i2,
                               unsigned short* __restrict__ o1, unsigned short* __restrict__ o2,
                               int n4, float* __restrict__ out, int outn) {
  int i = blockIdx.x * blockDim.x + threadIdx.x;
  if (i < outn) out[i] = 0.f;
  int stride = gridDim.x * blockDim.x;
  for (int j = i; j < n4; j += stride) {
    float4 v = ((const float4*)i1)[j];
    ushort4 r;
    r.x = f2bf(v.x); r.y = f2bf(v.y); r.z = f2bf(v.z); r.w = f2bf(v.w);
    ((ushort4*)o1)[j] = r;
    float4 u = ((const float4*)i2)[j];
    ushort4 q;
    q.x = f2bf(u.x); q.y = f2bf(u.y); q.z = f2bf(u.z); q.w = f2bf(u.w);
    ((ushort4*)o2)[j] = q;
  }
}

// ---------------- all-levels sort + selection + time chain, one launch --------
__global__ __launch_bounds__(1024) void sortall_kernel(
    const int* __restrict__ time0, int* __restrict__ sel_all) {
  int b = blockIdx.x;
  int tid = threadIdx.x;
  int lane = tid & 63, wid = tid >> 6;
  __shared__ int tcur[1024];
  __shared__ unsigned long long kl[1024];
  __shared__ int wcnt[16];
  __shared__ int tnew[512];

  tcur[tid] = time0[b * 1024 + tid];
  __syncthreads();

  int off = 0;
  for (int T = 1024; T >= 2; T >>= 1) {
    int n = T - 1, half = T >> 1;
    unsigned long long key = ~0ULL;
    if (tid < n) {
      unsigned d = (unsigned)(tcur[tid + 1] - tcur[tid]);
      key = ((unsigned long long)d << 10) | (unsigned)tid;
    }
    for (int size = 2; size <= T; size <<= 1) {
      bool up = ((tid & size) == 0);
      for (int stride = size >> 1; stride > 0; stride >>= 1) {
        bool lower = ((tid & stride) == 0);
        bool takemin = (lower == up);
        if (stride >= 64) {
          if (tid < T) kl[tid] = key;
          __syncthreads();
          if (tid < T) {
            unsigned long long pk = kl[tid ^ stride];
            unsigned long long mn = key < pk ? key : pk;
            unsigned long long mx = key < pk ? pk : key;
            key = takemin ? mn : mx;
          }
          __syncthreads();
        } else {
          unsigned klo = (unsigned)key, khi = (unsigned)(key >> 32);
          unsigned plo = __shfl_xor((int)klo, stride);
          unsigned phi = __shfl_xor((int)khi, stride);
          unsigned long long pk = ((unsigned long long)phi << 32) | plo;
          unsigned long long mn = key < pk ? key : pk;
          unsigned long long mx = key < pk ? pk : key;
          key = takemin ? mn : mx;
        }
      }
    }
    int p = (int)(key & 1023ULL);
    bool mask = (tid < n) && (p < half);
    unsigned long long bal = __ballot(mask);
    int rw = __popcll(bal & ((1ull << lane) - 1ull));
    if (lane == 0) wcnt[wid] = (int)__popcll(bal);
    __syncthreads();
    int pre = 0;
    for (int i = 0; i < wid; ++i) pre += wcnt[i];
    if (mask) {
      int rank = pre + rw;
      sel_all[off + b * half + rank] = tid;
      tnew[rank] = (tcur[tid] + tcur[tid + 1]) >> 1;
    }
    __syncthreads();
    if (tid < half) tcur[tid] = tnew[tid];
    off += 8 * half;
    __syncthreads();
  }
}

// ---------------- pool chain: LDS-resident d-slice, all 10 levels ----------
// blocks = 8 b x 2 z-array x 20 d-chunks (16 bf16). Level l slice lives in
// LDS (ping-pong A/B); global writes are fire-and-forget for mega.
__global__ __launch_bounds__(256, 2) void poolchain_kernel(
    const int* __restrict__ sel_all,
    unsigned short* __restrict__ z1, unsigned short* __restrict__ z2) {
  int bx = blockIdx.x;
  int tid = threadIdx.x;
  int chunk = bx % 20;
  int zi = (bx / 20) & 1;
  int b = bx / 40;
  unsigned short* z = (zi == 0) ? z1 : z2;

  __shared__ unsigned short zsA[1024][18];
  __shared__ unsigned short zsB[512][18];

  // load level0 slice (rows 0..1023, cols chunk*16..+15)
  const unsigned short* src0 = z + ((size_t)b * 1024) * D_DIM + chunk * 16;
  for (int u = tid; u < 1024 * 2; u += 256) {
    int r = u >> 1, h = u & 1;
    *(bf16x8_t*)&zsA[r][h * 8] = *(const bf16x8_t*)(src0 + (size_t)r * D_DIM + h * 8);
  }
  __syncthreads();

  int off = 0;
  size_t zo = (size_t)8 * 1024 * D_DIM;
  for (int l = 0; l < 10; ++l) {
    int T = 1024 >> l, half = T >> 1;
    const int* selp = sel_all + off + b * half;
    unsigned short* dst = z + zo + ((size_t)b * half) * D_DIM + chunk * 16;
    bool AtoB = ((l & 1) == 0);
    for (int u = tid; u < half * 2; u += 256) {
      int j = u >> 1, h = u & 1;
      int k = selp[j];
      bf16x8_t a, c;
      if (AtoB) {
        a = *(const bf16x8_t*)&zsA[k][h * 8];
        c = *(const bf16x8_t*)&zsA[k + 1][h * 8];
      } else {
        a = *(const bf16x8_t*)&zsB[k][h * 8];
        c = *(const bf16x8_t*)&zsB[k + 1][h * 8];
      }
      bf16x8_t rv;
#pragma unroll
      for (int e = 0; e < 8; ++e)
        rv[e] = (bf2f((unsigned short)a[e]) >= bf2f((unsigned short)c[e])) ? a[e] : c[e];
      *(bf16x8_t*)(dst + (size_t)j * D_DIM + h * 8) = rv;
      if (AtoB) *(bf16x8_t*)&zsB[j][h * 8] = rv;
      else      *(bf16x8_t*)&zsA[j][h * 8] = rv;
    }
    __syncthreads();
    off += 8 * half;
    zo += (size_t)8 * half * D_DIM;
  }
}

// ---------------- mega: ALL levels' temporal tiles + instance blocks ----------
__global__ __launch_bounds__(256, 4) void mega_kernel(
    const unsigned short* __restrict__ z1, const unsigned short* __restrict__ z2,
    float* __restrict__ wsm, float* __restrict__ wss,
    float* __restrict__ out, Tab tab) {
  __shared__ __align__(16) unsigned char smem[36864];
  int bx = blockIdx.x;
  int tid = threadIdx.x;

  if (bx < tab.totTemp) {
    // ================= temporal: one 128x128 tile, counted-vmcnt pipeline ====
    int l = 0;
    while (bx >= tab.tileStart[l + 1]) ++l;
    int T = tab.T[l], S = tab.S[l];
    int N = 2 * T;
    const unsigned short* zz1 = z1 + tab.zoff[l];
    const unsigned short* zz2 = z2 + tab.zoff[l];
    float* wm = wsm + tab.wsoff[l];
    float* wv = wss + tab.wsoff[l];

    int local = bx - tab.tileStart[l];
    int nTl = 8 * S * S;
    int nid = (local % 8) * (nTl / 8) + local / 8;
    int TPB = S * S;
    int b = nid / TPB;
    int r = nid % TPB;
    int sgb = (S < 4) ? S : 4;
    int ic = sgb * sgb;
    int ci = r / ic, ii = r % ic;
    int ncx = S / sgb;
    int cx = ci % ncx, cy = ci / ncx;
    int sg = cx * sgb + ii % sgb;
    int rb = cy * sgb + ii / sgb;
    int row0 = rb * 128, col0 = sg * 128;

    int w = tid >> 6, lane = tid & 63;
    int lq = lane >> 4, lr = lane & 15;
    int wr = w >> 1, wc = w & 1;

    unsigned short* lds = (unsigned short*)smem;            // 32768 B
    float (*mS)[128] = (float(*)[128])(smem + 32768);
    float (*sS)[128] = (float(*)[128])(smem + 33792);

    auto stage = [&](int k, int buf) {
      int kp = k * 4;
#pragma unroll
      for (int i = 0; i < 2; ++i) {
        int h = i * 64;
        {
          int gr = row0 + h + lane;
          if (gr > N - 1) gr = N - 1;
          GLOAD_LDS16(zrowb(zz1, zz2, b, T, gr) + (kp + w) * 8,
                      &lds[(((buf * 2 + 0) * 4 + w) * 128 + h + lane) * 8]);
        }
        {
          int gc = col0 + h + lane;
          if (gc > N - 1) gc = N - 1;
          GLOAD_LDS16(zrowb(zz1, zz2, b, T, gc) + (kp + w) * 8,
                      &lds[(((buf * 2 + 1) * 4 + w) * 128 + h + lane) * 8]);
        }
      }
    };

    f32x4_t acc[4][4];
#pragma unroll
    for (int at = 0; at < 4; ++at)
#pragma unroll
      for (int ct = 0; ct < 4; ++ct) acc[at][ct] = (f32x4_t)(0.f);

    stage(0, 0);   // 4 vmem ops/wave
    stage(1, 1);   // +4 -> 8 outstanding

    for (int k = 0; k < 10; ++k) {
      int buf = k & 1;
      // wait for stage(k) only; keep stage(k+1) (and later k+2) in flight
      if (k < 9) asm volatile("s_waitcnt vmcnt(4)" ::: "memory");
      else       asm volatile("s_waitcnt vmcnt(0)" ::: "memory");
      __builtin_amdgcn_s_barrier();

      bf16x8_t af[4], bfr[4];
#pragma unroll
      for (int at = 0; at < 4; ++at)
        af[at] = *(const bf16x8_t*)&lds[(((buf * 2 + 0) * 4 + lq) * 128 + wr * 64 + at * 16 + lr) * 8];
#pragma unroll
      for (int ct = 0; ct < 4; ++ct)
        bfr[ct] = *(const bf16x8_t*)&lds[(((buf * 2 + 1) * 4 + lq) * 128 + wc * 64 + ct * 16 + lr) * 8];
      asm volatile("s_waitcnt lgkmcnt(0)" ::: "memory");
      __builtin_amdgcn_sched_barrier(0);
      __builtin_amdgcn_s_barrier();  // all waves done reading buf

      if (k + 2 < 10) stage(k + 2, buf);  // overwrite buf; hidden under MFMA

      __builtin_amdgcn_s_setprio(1);
#pragma unroll
      for (int ct = 0; ct < 4; ++ct)
#pragma unroll
        for (int at = 0; at < 4; ++at)
          acc[at][ct] = __builtin_amdgcn_mfma_f32_16x16x32_bf16(af[at], bfr[ct], acc[at][ct], 0, 0, 0);
      __builtin_amdgcn_s_setprio(0);
    }
    __builtin_amdgcn_s_barrier();

    // two-pass LSE over this block's 128 cols
#pragma unroll
    for (int at = 0; at < 4; ++at) {
#pragma unroll
      for (int rg = 0; rg < 4; ++rg) {
        int rloc = wr * 64 + at * 16 + lq * 4 + rg;
        int rglob = row0 + rloc;
        float v[4];
#pragma unroll
        for (int ct = 0; ct < 4; ++ct) {
          int cg = col0 + wc * 64 + ct * 16 + lr;
          v[ct] = (cg < N && cg != rglob) ? acc[at][ct][rg] : NEGINF;
        }
        float m = fmaxf(fmaxf(v[0], v[1]), fmaxf(v[2], v[3]));
#pragma unroll
        for (int o = 1; o < 16; o <<= 1) m = fmaxf(m, __shfl_xor(m, o));
        float sv = __expf(v[0] - m) + __expf(v[1] - m) +
                   __expf(v[2] - m) + __expf(v[3] - m);
#pragma unroll
        for (int o = 1; o < 16; o <<= 1) sv += __shfl_xor(sv, o);
        if (lr == 0) { mS[wc][rloc] = m; sS[wc][rloc] = sv; }
      }
    }
    __syncthreads();

    if (tid < 128) {
      int rglob = row0 + tid;
      if (rglob < N) {
        float m0 = mS[0][tid], m1 = mS[1][tid];
        float m = fmaxf(m0, m1);
        float sv = sS[0][tid] * __expf(m0 - m) + sS[1][tid] * __expf(m1 - m);
        int idx = (b * S + sg) * N + rglob;
        wm[idx] = m;
        wv[idx] = sv;
      }
    }
  } else {
    // ================= instance loss =================
    int ix = bx - tab.totTemp;
    int l = 0;
    while (ix >= tab.instStart[l + 1]) ++l;
    int t = ix - tab.instStart[l];
    int T = tab.T[l];
    const unsigned short* zz1 = z1 + tab.zoff[l];
    const unsigned short* zz2 = z2 + tab.zoff[l];
    float scale = tab.scale[l];

    unsigned short (*Zs)[328] = (unsigned short(*)[328])smem;
    float (*Ss)[17] = (float(*)[17])(smem + 10496);
    float* Ls = (float*)(smem + 11584);
    for (int c = tid; c < 640; c += 256) {
      int i = c / 40, ko = c % 40;
      const unsigned short* p = (i < 8) ? (zz1 + ((size_t)i * T + t) * D_DIM)
                                        : (zz2 + ((size_t)(i - 8) * T + t) * D_DIM);
      *(bf16x8_t*)&Zs[i][ko * 8] = *(const bf16x8_t*)(p + ko * 8);
    }
    __syncthreads();

    int i = tid >> 4, j = tid & 15;
    float dot = 0.f;
    for (int k = 0; k < 40; ++k) {
      bf16x8_t a = *(const bf16x8_t*)&Zs[i][k * 8];
      bf16x8_t bb = *(const bf16x8_t*)&Zs[j][k * 8];
#pragma unroll
      for (int e = 0; e < 8; ++e)
        dot += bf2f((unsigned short)a[e]) * bf2f((unsigned short)bb[e]);
    }
    Ss[i][j] = dot;
    __syncthreads();

    if (tid < 16) {
      int rr = tid;
      float m = NEGINF;
      for (int c = 0; c < 16; ++c) if (c != rr) m = fmaxf(m, Ss[rr][c]);
      float s = 0.f;
      for (int c = 0; c < 16; ++c) if (c != rr) s += __expf(Ss[rr][c] - m);
      int pos = (rr < 8) ? rr + 8 : rr - 8;
      Ls[rr] = m + logf(s) - Ss[rr][pos];
    }
    __syncthreads();
    if (tid == 0) {
      float sum = 0.f;
      for (int rr = 0; rr < 16; ++rr) sum += Ls[rr];
      atomicAdd(out, sum * scale);
    }
  }
}

// ---------------- combine all levels' temporal partials, one launch ----------
__global__ __launch_bounds__(256) void combine_kernel(
    const unsigned short* __restrict__ z1, const unsigned short* __restrict__ z2,
    const float* __restrict__ wsm, const float* __restrict__ wss,
    float* __restrict__ out, Tab tab) {
  int g = blockIdx.x * 256 + threadIdx.x;
  float loss = 0.f;
  if (g < tab.totr) {
    int l = 0;
    while (g >= tab.rstart[l + 1]) ++l;
    int row = g - tab.rstart[l];
    int T = tab.T[l], N = 2 * T, S = tab.S[l];
    int b = row / N, r = row % N;
    const float* wm = wsm + tab.wsoff[l];
    const float* wv = wss + tab.wsoff[l];
    float m = NEGINF;
    for (int s = 0; s < S; ++s) m = fmaxf(m, wm[(b * S + s) * N + r]);
    float sv = 0.f;
    for (int s = 0; s < S; ++s) {
      int idx = (b * S + s) * N + r;
      sv += wv[idx] * __expf(wm[idx] - m);
    }
    const unsigned short* zz1 = z1 + tab.zoff[l];
    const unsigned short* zz2 = z2 + tab.zoff[l];
    int pos = (r < T) ? r + T : r - T;
    const bf16x8_t* za = (const bf16x8_t*)zrowb(zz1, zz2, b, T, r);
    const bf16x8_t* zp = (const bf16x8_t*)zrowb(zz1, zz2, b, T, pos);
    float dot = 0.f;
    for (int k = 0; k < D_DIM / 8; ++k) {
      bf16x8_t a = za[k], p = zp[k];
#pragma unroll
      for (int e = 0; e < 8; ++e)
        dot += bf2f((unsigned short)a[e]) * bf2f((unsigned short)p[e]);
    }
    loss = (m + logf(sv) - dot) * tab.scale[l];
  }
  float v = loss;
#pragma unroll
  for (int o = 1; o < 64; o <<= 1) v += __shfl_xor(v, o);
  __shared__ float part[4];
  int w = threadIdx.x >> 6;
  if ((threadIdx.x & 63) == 0) part[w] = v;
  __syncthreads();
  if (threadIdx.x == 0)
    atomicAdd(out, part[0] + part[1] + part[2] + part[3]);
}

extern "C" void kernel_launch(void* const* d_in, const int* in_sizes, int n_in,
                              void* d_out, int out_size, void* d_ws, size_t ws_size,
                              hipStream_t stream) {
  const float* z1_in = (const float*)d_in[0];
  const float* z2_in = (const float*)d_in[1];
  const int* time_in = (const int*)d_in[2];
  float* out = (float*)d_out;

  // ---- build level tables ----
  Tab tab;
  int zo = 0, wso = 0, ts = 0, is = 0, rs = 0;
  for (int l = 0; l < 11; ++l) {
    int T = 1024 >> l, N = 2 * T;
    int S = (N >= 128) ? N / 128 : 1;
    tab.T[l] = T;
    tab.S[l] = S;
    tab.zoff[l] = zo;
    tab.scale[l] = 1.0f / (352.0f * (float)T);  // 0.5/(2*B*T)/11
    tab.tileStart[l] = ts;
    tab.instStart[l] = is;
    tab.wsoff[l] = (T > 1) ? wso : 0;
    if (l < 10) tab.rstart[l] = rs;
    if (T > 1) {
      ts += 8 * S * S;
      wso += 8 * S * N;
      rs += 8 * N;
    }
    is += T;
    zo += 8 * T * D_DIM;
  }
  tab.tileStart[11] = ts;
  tab.instStart[11] = is;
  tab.rstart[10] = rs;
  tab.totTemp = ts;
  tab.totInst = is;
  tab.totr = rs;

  // ---- workspace carve ----
  char* w = (char*)d_ws;
  unsigned short* z1s = (unsigned short*)w; w += (size_t)zo * 2;
  unsigned short* z2s = (unsigned short*)w; w += (size_t)zo * 2;
  int* sel_all = (int*)w; w += 8192 * sizeof(int);
  float* wsm = (float*)w; w += (size_t)wso * sizeof(float);
  float* wss = (float*)w; w += (size_t)wso * sizeof(float);

  int n0 = 8 * 1024 * D_DIM;
  convert_kernel<<<2048, 256, 0, stream>>>(z1_in, z2_in, z1s, z2s, n0 / 4,
                                           out, out_size);
  sortall_kernel<<<8, 1024, 0, stream>>>(time_in, sel_all);
  poolchain_kernel<<<320, 256, 0, stream>>>(sel_all, z1s, z2s);
  mega_kernel<<<ts + is, 256, 0, stream>>>(z1s, z2s, wsm, wss, out, tab);
  combine_kernel<<<(rs + 255) / 256, 256, 0, stream>>>(z1s, z2s, wsm, wss, out, tab);
}

// Round 8
// 173.451 us; speedup vs baseline: 9.4492x; 1.0371x over previous
//
#include <hip/hip_runtime.h>
#include <cstdint>
#include <cstddef>

#define D_DIM 320
#define NEGINF (-1e30f)

typedef __attribute__((ext_vector_type(8))) short bf16x8_t;
typedef __attribute__((ext_vector_type(4))) float f32x4_t;

struct Tab {
  int T[11], S[11], zoff[11], wsoff[11];
  int tileStart[12], instStart[12], rstart[11];
  float scale[11];
  int totTemp, totInst, totr;
};

__device__ __forceinline__ float bf2f(unsigned short u) {
  union { unsigned int i; float f; } v; v.i = ((unsigned int)u) << 16; return v.f;
}
__device__ __forceinline__ unsigned short f2bf(float f) {
  union { float f; unsigned int i; } u; u.f = f;
  unsigned int b = u.i + 0x7FFFu + ((u.i >> 16) & 1u);
  return (unsigned short)(b >> 16);
}

__device__ __forceinline__ const unsigned short* zrowb(
    const unsigned short* __restrict__ z1, const unsigned short* __restrict__ z2,
    int b, int T, int r) {
  return (r < T) ? (z1 + ((size_t)b * T + r) * D_DIM)
                 : (z2 + ((size_t)b * T + (r - T)) * D_DIM);
}

#define GLOAD_LDS16(SRC, DST)                                                   \
  __builtin_amdgcn_global_load_lds(                                             \
      (const __attribute__((address_space(1))) void*)(SRC),                     \
      (__attribute__((address_space(3))) void*)(DST), 16, 0, 0)

// ---------------- fp32 -> bf16 convert (both arrays) + zero out ----------------
__global__ void convert_kernel(const float* __restrict__ i1, const float* __restrict__ i2,
                               unsigned short* __restrict__ o1, unsigned short* __restrict__ o2,
                               int n4, float* __restrict__ out, int outn) {
  int i = blockIdx.x * blockDim.x + threadIdx.x;
  if (i < outn) out[i] = 0.f;
  int stride = gridDim.x * blockDim.x;
  for (int j = i; j < n4; j += stride) {
    float4 v = ((const float4*)i1)[j];
    ushort4 r;
    r.x = f2bf(v.x); r.y = f2bf(v.y); r.z = f2bf(v.z); r.w = f2bf(v.w);
    ((ushort4*)o1)[j] = r;
    float4 u = ((const float4*)i2)[j];
    ushort4 q;
    q.x = f2bf(u.x); q.y = f2bf(u.y); q.z = f2bf(u.z); q.w = f2bf(u.w);
    ((ushort4*)o2)[j] = q;
  }
}

// ---------------- all-levels sort + selection + time chain, one launch --------
__global__ __launch_bounds__(1024) void sortall_kernel(
    const int* __restrict__ time0, int* __restrict__ sel_all) {
  int b = blockIdx.x;
  int tid = threadIdx.x;
  int lane = tid & 63, wid = tid >> 6;
  __shared__ int tcur[1024];
  __shared__ unsigned long long kl[1024];
  __shared__ int wcnt[16];
  __shared__ int tnew[512];

  tcur[tid] = time0[b * 1024 + tid];
  __syncthreads();

  int off = 0;
  for (int T = 1024; T >= 2; T >>= 1) {
    int n = T - 1, half = T >> 1;
    unsigned long long key = ~0ULL;
    if (tid < n) {
      unsigned d = (unsigned)(tcur[tid + 1] - tcur[tid]);
      key = ((unsigned long long)d << 10) | (unsigned)tid;
    }
    for (int size = 2; size <= T; size <<= 1) {
      bool up = ((tid & size) == 0);
      for (int stride = size >> 1; stride > 0; stride >>= 1) {
        bool lower = ((tid & stride) == 0);
        bool takemin = (lower == up);
        if (stride >= 64) {
          if (tid < T) kl[tid] = key;
          __syncthreads();
          if (tid < T) {
            unsigned long long pk = kl[tid ^ stride];
            unsigned long long mn = key < pk ? key : pk;
            unsigned long long mx = key < pk ? pk : key;
            key = takemin ? mn : mx;
          }
          __syncthreads();
        } else {
          unsigned klo = (unsigned)key, khi = (unsigned)(key >> 32);
          unsigned plo = __shfl_xor((int)klo, stride);
          unsigned phi = __shfl_xor((int)khi, stride);
          unsigned long long pk = ((unsigned long long)phi << 32) | plo;
          unsigned long long mn = key < pk ? key : pk;
          unsigned long long mx = key < pk ? pk : key;
          key = takemin ? mn : mx;
        }
      }
    }
    int p = (int)(key & 1023ULL);
    bool mask = (tid < n) && (p < half);
    unsigned long long bal = __ballot(mask);
    int rw = __popcll(bal & ((1ull << lane) - 1ull));
    if (lane == 0) wcnt[wid] = (int)__popcll(bal);
    __syncthreads();
    int pre = 0;
    for (int i = 0; i < wid; ++i) pre += wcnt[i];
    if (mask) {
      int rank = pre + rw;
      sel_all[off + b * half + rank] = tid;
      tnew[rank] = (tcur[tid] + tcur[tid + 1]) >> 1;
    }
    __syncthreads();
    if (tid < half) tcur[tid] = tnew[tid];
    off += 8 * half;
    __syncthreads();
  }
}

// ---------------- pool chain: LDS-resident d-slice, all 10 levels ----------
__global__ __launch_bounds__(256, 2) void poolchain_kernel(
    const int* __restrict__ sel_all,
    unsigned short* __restrict__ z1, unsigned short* __restrict__ z2) {
  int bx = blockIdx.x;
  int tid = threadIdx.x;
  int chunk = bx % 20;
  int zi = (bx / 20) & 1;
  int b = bx / 40;
  unsigned short* z = (zi == 0) ? z1 : z2;

  __shared__ unsigned short zsA[1024][18];
  __shared__ unsigned short zsB[512][18];

  const unsigned short* src0 = z + ((size_t)b * 1024) * D_DIM + chunk * 16;
  for (int u = tid; u < 1024 * 2; u += 256) {
    int r = u >> 1, h = u & 1;
    *(bf16x8_t*)&zsA[r][h * 8] = *(const bf16x8_t*)(src0 + (size_t)r * D_DIM + h * 8);
  }
  __syncthreads();

  int off = 0;
  size_t zo = (size_t)8 * 1024 * D_DIM;
  for (int l = 0; l < 10; ++l) {
    int T = 1024 >> l, half = T >> 1;
    const int* selp = sel_all + off + b * half;
    unsigned short* dst = z + zo + ((size_t)b * half) * D_DIM + chunk * 16;
    bool AtoB = ((l & 1) == 0);
    for (int u = tid; u < half * 2; u += 256) {
      int j = u >> 1, h = u & 1;
      int k = selp[j];
      bf16x8_t a, c;
      if (AtoB) {
        a = *(const bf16x8_t*)&zsA[k][h * 8];
        c = *(const bf16x8_t*)&zsA[k + 1][h * 8];
      } else {
        a = *(const bf16x8_t*)&zsB[k][h * 8];
        c = *(const bf16x8_t*)&zsB[k + 1][h * 8];
      }
      bf16x8_t rv;
#pragma unroll
      for (int e = 0; e < 8; ++e)
        rv[e] = (bf2f((unsigned short)a[e]) >= bf2f((unsigned short)c[e])) ? a[e] : c[e];
      *(bf16x8_t*)(dst + (size_t)j * D_DIM + h * 8) = rv;
      if (AtoB) *(bf16x8_t*)&zsB[j][h * 8] = rv;
      else      *(bf16x8_t*)&zsA[j][h * 8] = rv;
    }
    __syncthreads();
    off += 8 * half;
    zo += (size_t)8 * half * D_DIM;
  }
}

// ---------------- mega: ALL levels' temporal tiles + instance waves ----------
__global__ __launch_bounds__(256, 4) void mega_kernel(
    const unsigned short* __restrict__ z1, const unsigned short* __restrict__ z2,
    float* __restrict__ wsm, float* __restrict__ wss,
    float* __restrict__ out, Tab tab) {
  __shared__ __align__(16) unsigned char smem[36864];
  int bx = blockIdx.x;
  int tid = threadIdx.x;

  if (bx < tab.totTemp) {
    // ================= temporal: one 128x128 tile, hoisted-address pipeline ==
    int l = 0;
    while (bx >= tab.tileStart[l + 1]) ++l;
    int T = tab.T[l], S = tab.S[l];
    int N = 2 * T;
    const unsigned short* zz1 = z1 + tab.zoff[l];
    const unsigned short* zz2 = z2 + tab.zoff[l];
    float* wm = wsm + tab.wsoff[l];
    float* wv = wss + tab.wsoff[l];

    int local = bx - tab.tileStart[l];
    int nTl = 8 * S * S;
    int nid = (local % 8) * (nTl / 8) + local / 8;
    int TPB = S * S;
    int b = nid / TPB;
    int r = nid % TPB;
    int sgb = (S < 4) ? S : 4;
    int ic = sgb * sgb;
    int ci = r / ic, ii = r % ic;
    int ncx = S / sgb;
    int cx = ci % ncx, cy = ci / ncx;
    int sg = cx * sgb + ii % sgb;
    int rb = cy * sgb + ii / sgb;
    int row0 = rb * 128, col0 = sg * 128;

    int w = tid >> 6, lane = tid & 63;
    int lq = lane >> 4, lr = lane & 15;
    int wr = w >> 1, wc = w & 1;

    unsigned short* lds = (unsigned short*)smem;            // 32768 B
    float (*mS)[128] = (float(*)[128])(smem + 32768);
    float (*sS)[128] = (float(*)[128])(smem + 33792);

    // ---- hoisted per-wave global sources (rows/cols fixed; only K advances)
    int ra0 = row0 + lane;        if (ra0 > N - 1) ra0 = N - 1;
    int ra1 = row0 + 64 + lane;   if (ra1 > N - 1) ra1 = N - 1;
    int ca0 = col0 + lane;        if (ca0 > N - 1) ca0 = N - 1;
    int ca1 = col0 + 64 + lane;   if (ca1 > N - 1) ca1 = N - 1;
    const unsigned short* gA0 = zrowb(zz1, zz2, b, T, ra0) + w * 8;
    const unsigned short* gA1 = zrowb(zz1, zz2, b, T, ra1) + w * 8;
    const unsigned short* gB0 = zrowb(zz1, zz2, b, T, ca0) + w * 8;
    const unsigned short* gB1 = zrowb(zz1, zz2, b, T, ca1) + w * 8;
    // fixed LDS destinations (buf selects by literal offset)
    unsigned short* dA0 = &lds[((w) * 128 + lane) * 8];
    unsigned short* dA1 = &lds[((w) * 128 + 64 + lane) * 8];
    unsigned short* dB0 = &lds[((4 + w) * 128 + lane) * 8];
    unsigned short* dB1 = &lds[((4 + w) * 128 + 64 + lane) * 8];

    // stage K-step k into buffer buf (buf literal; koff = k*32 elements)
#define STAGE(koff, bufofs)                                                     \
    do {                                                                        \
      GLOAD_LDS16(gA0 + (koff), dA0 + (bufofs));                                \
      GLOAD_LDS16(gA1 + (koff), dA1 + (bufofs));                                \
      GLOAD_LDS16(gB0 + (koff), dB0 + (bufofs));                                \
      GLOAD_LDS16(gB1 + (koff), dB1 + (bufofs));                                \
    } while (0)

    f32x4_t acc[4][4];
#pragma unroll
    for (int at = 0; at < 4; ++at)
#pragma unroll
      for (int ct = 0; ct < 4; ++ct) acc[at][ct] = (f32x4_t)(0.f);

    // frag-read bases (buf/at/ct fold to imm offsets)
    const unsigned short* vA = &lds[((lq) * 128 + wr * 64 + lr) * 8];
    const unsigned short* vB = &lds[((4 + lq) * 128 + wc * 64 + lr) * 8];
#define BUFOFS 8192  /* shorts: 8 planes *128 rows *8 */

    STAGE(0, 0);
    STAGE(32, BUFOFS);

    // one phase: literal buf offset, counted vmcnt, prefetch next-next
#define PHASE(k, bo, other_bo, VM, DO_PF)                                       \
    do {                                                                        \
      asm volatile("s_waitcnt vmcnt(" #VM ")" ::: "memory");                    \
      __builtin_amdgcn_s_barrier();                                             \
      bf16x8_t af[4], bfr[4];                                                   \
      _Pragma("unroll")                                                         \
      for (int at = 0; at < 4; ++at)                                            \
        af[at] = *(const bf16x8_t*)(vA + (bo) + at * 128);                      \
      _Pragma("unroll")                                                         \
      for (int ct = 0; ct < 4; ++ct)                                            \
        bfr[ct] = *(const bf16x8_t*)(vB + (bo) + ct * 128);                     \
      asm volatile("s_waitcnt lgkmcnt(0)" ::: "memory");                        \
      __builtin_amdgcn_sched_barrier(0);                                        \
      __builtin_amdgcn_s_barrier();                                             \
      if (DO_PF) STAGE((k + 2) * 32, bo);                                       \
      __builtin_amdgcn_s_setprio(1);                                            \
      _Pragma("unroll")                                                         \
      for (int ct = 0; ct < 4; ++ct)                                            \
        _Pragma("unroll")                                                       \
        for (int at = 0; at < 4; ++at)                                          \
          acc[at][ct] = __builtin_amdgcn_mfma_f32_16x16x32_bf16(                \
              af[at], bfr[ct], acc[at][ct], 0, 0, 0);                           \
      __builtin_amdgcn_s_setprio(0);                                            \
    } while (0)

    for (int k = 0; k < 8; k += 2) {
      PHASE(k, 0, BUFOFS, 4, 1);
      PHASE(k + 1, BUFOFS, 0, 4, 1);
    }
    PHASE(8, 0, BUFOFS, 4, 0);
    PHASE(9, BUFOFS, 0, 0, 0);
#undef PHASE
#undef STAGE
    __builtin_amdgcn_s_barrier();

    // two-pass LSE over this block's 128 cols
#pragma unroll
    for (int at = 0; at < 4; ++at) {
#pragma unroll
      for (int rg = 0; rg < 4; ++rg) {
        int rloc = wr * 64 + at * 16 + lq * 4 + rg;
        int rglob = row0 + rloc;
        float v[4];
#pragma unroll
        for (int ct = 0; ct < 4; ++ct) {
          int cg = col0 + wc * 64 + ct * 16 + lr;
          v[ct] = (cg < N && cg != rglob) ? acc[at][ct][rg] : NEGINF;
        }
        float m = fmaxf(fmaxf(v[0], v[1]), fmaxf(v[2], v[3]));
#pragma unroll
        for (int o = 1; o < 16; o <<= 1) m = fmaxf(m, __shfl_xor(m, o));
        float sv = __expf(v[0] - m) + __expf(v[1] - m) +
                   __expf(v[2] - m) + __expf(v[3] - m);
#pragma unroll
        for (int o = 1; o < 16; o <<= 1) sv += __shfl_xor(sv, o);
        if (lr == 0) { mS[wc][rloc] = m; sS[wc][rloc] = sv; }
      }
    }
    __syncthreads();

    if (tid < 128) {
      int rglob = row0 + tid;
      if (rglob < N) {
        float m0 = mS[0][tid], m1 = mS[1][tid];
        float m = fmaxf(m0, m1);
        float sv = sS[0][tid] * __expf(m0 - m) + sS[1][tid] * __expf(m1 - m);
        int idx = (b * S + sg) * N + rglob;
        wm[idx] = m;
        wv[idx] = sv;
      }
    }
  } else {
    // ================= instance loss: one wave per t, MFMA Z·Z^T =============
    int iw = (bx - tab.totTemp) * 4 + (tid >> 6);
    if (iw < tab.totInst) {
      int l = 0;
      while (iw >= tab.instStart[l + 1]) ++l;
      int t = iw - tab.instStart[l];
      int T = tab.T[l];
      const unsigned short* zz1 = z1 + tab.zoff[l];
      const unsigned short* zz2 = z2 + tab.zoff[l];
      int lane = tid & 63, lq = lane >> 4, lr = lane & 15;
      const unsigned short* zr = (lr < 8)
          ? zz1 + ((size_t)lr * T + t) * D_DIM
          : zz2 + ((size_t)(lr - 8) * T + t) * D_DIM;
      zr += lq * 8;
      f32x4_t c = (f32x4_t)(0.f);
#pragma unroll
      for (int k = 0; k < 10; ++k) {
        bf16x8_t a = *(const bf16x8_t*)(zr + k * 32);
        // B-frag of Z·Z^T equals A-frag (col=lane&15 holds Z[col][kslice])
        c = __builtin_amdgcn_mfma_f32_16x16x32_bf16(a, a, c, 0, 0, 0);
      }
      float lsum = 0.f;
#pragma unroll
      for (int rg = 0; rg < 4; ++rg) {
        int rrow = lq * 4 + rg;
        float v = c[rg];
        float x = (lr != rrow) ? v : NEGINF;
        float m = x;
#pragma unroll
        for (int o = 1; o < 16; o <<= 1) m = fmaxf(m, __shfl_xor(m, o));
        float s = __expf(x - m);
#pragma unroll
        for (int o = 1; o < 16; o <<= 1) s += __shfl_xor(s, o);
        int pos = (rrow < 8) ? rrow + 8 : rrow - 8;
        if (lr == pos) lsum += m + __logf(s) - v;
      }
#pragma unroll
      for (int o = 1; o < 64; o <<= 1) lsum += __shfl_xor(lsum, o);
      if (lane == 0) atomicAdd(out, lsum * tab.scale[l]);
    }
  }
}

// ---------------- combine all levels' temporal partials, one launch ----------
__global__ __launch_bounds__(256) void combine_kernel(
    const unsigned short* __restrict__ z1, const unsigned short* __restrict__ z2,
    const float* __restrict__ wsm, const float* __restrict__ wss,
    float* __restrict__ out, Tab tab) {
  int g = blockIdx.x * 256 + threadIdx.x;
  float loss = 0.f;
  if (g < tab.totr) {
    int l = 0;
    while (g >= tab.rstart[l + 1]) ++l;
    int row = g - tab.rstart[l];
    int T = tab.T[l], N = 2 * T, S = tab.S[l];
    int b = row / N, r = row % N;
    const float* wm = wsm + tab.wsoff[l];
    const float* wv = wss + tab.wsoff[l];
    float m = NEGINF;
    for (int s = 0; s < S; ++s) m = fmaxf(m, wm[(b * S + s) * N + r]);
    float sv = 0.f;
    for (int s = 0; s < S; ++s) {
      int idx = (b * S + s) * N + r;
      sv += wv[idx] * __expf(wm[idx] - m);
    }
    const unsigned short* zz1 = z1 + tab.zoff[l];
    const unsigned short* zz2 = z2 + tab.zoff[l];
    int pos = (r < T) ? r + T : r - T;
    const bf16x8_t* za = (const bf16x8_t*)zrowb(zz1, zz2, b, T, r);
    const bf16x8_t* zp = (const bf16x8_t*)zrowb(zz1, zz2, b, T, pos);
    float dot = 0.f;
    for (int k = 0; k < D_DIM / 8; ++k) {
      bf16x8_t a = za[k], p = zp[k];
#pragma unroll
      for (int e = 0; e < 8; ++e)
        dot += bf2f((unsigned short)a[e]) * bf2f((unsigned short)p[e]);
    }
    loss = (m + logf(sv) - dot) * tab.scale[l];
  }
  float v = loss;
#pragma unroll
  for (int o = 1; o < 64; o <<= 1) v += __shfl_xor(v, o);
  __shared__ float part[4];
  int w = threadIdx.x >> 6;
  if ((threadIdx.x & 63) == 0) part[w] = v;
  __syncthreads();
  if (threadIdx.x == 0)
    atomicAdd(out, part[0] + part[1] + part[2] + part[3]);
}

extern "C" void kernel_launch(void* const* d_in, const int* in_sizes, int n_in,
                              void* d_out, int out_size, void* d_ws, size_t ws_size,
                              hipStream_t stream) {
  const float* z1_in = (const float*)d_in[0];
  const float* z2_in = (const float*)d_in[1];
  const int* time_in = (const int*)d_in[2];
  float* out = (float*)d_out;

  // ---- build level tables ----
  Tab tab;
  int zo = 0, wso = 0, ts = 0, is = 0, rs = 0;
  for (int l = 0; l < 11; ++l) {
    int T = 1024 >> l, N = 2 * T;
    int S = (N >= 128) ? N / 128 : 1;
    tab.T[l] = T;
    tab.S[l] = S;
    tab.zoff[l] = zo;
    tab.scale[l] = 1.0f / (352.0f * (float)T);  // 0.5/(2*B*T)/11
    tab.tileStart[l] = ts;
    tab.instStart[l] = is;
    tab.wsoff[l] = (T > 1) ? wso : 0;
    if (l < 10) tab.rstart[l] = rs;
    if (T > 1) {
      ts += 8 * S * S;
      wso += 8 * S * N;
      rs += 8 * N;
    }
    is += T;
    zo += 8 * T * D_DIM;
  }
  tab.tileStart[11] = ts;
  tab.instStart[11] = is;
  tab.rstart[10] = rs;
  tab.totTemp = ts;
  tab.totInst = is;
  tab.totr = rs;

  // ---- workspace carve ----
  char* w = (char*)d_ws;
  unsigned short* z1s = (unsigned short*)w; w += (size_t)zo * 2;
  unsigned short* z2s = (unsigned short*)w; w += (size_t)zo * 2;
  int* sel_all = (int*)w; w += 8192 * sizeof(int);
  float* wsm = (float*)w; w += (size_t)wso * sizeof(float);
  float* wss = (float*)w; w += (size_t)wso * sizeof(float);

  int n0 = 8 * 1024 * D_DIM;
  convert_kernel<<<2048, 256, 0, stream>>>(z1_in, z2_in, z1s, z2s, n0 / 4,
                                           out, out_size);
  sortall_kernel<<<8, 1024, 0, stream>>>(time_in, sel_all);
  poolchain_kernel<<<320, 256, 0, stream>>>(sel_all, z1s, z2s);
  int nInstB = (is + 3) / 4;
  mega_kernel<<<ts + nInstB, 256, 0, stream>>>(z1s, z2s, wsm, wss, out, tab);
  combine_kernel<<<(rs + 255) / 256, 256, 0, stream>>>(z1s, z2s, wsm, wss, out, tab);
}

// Round 9
// 131.600 us; speedup vs baseline: 12.4542x; 1.3180x over previous
//
#include <hip/hip_runtime.h>
#include <cstdint>
#include <cstddef>

#define D_DIM 320
#define NEGINF (-1e30f)

typedef __attribute__((ext_vector_type(8))) short bf16x8_t;
typedef __attribute__((ext_vector_type(4))) float f32x4_t;

struct Tab {
  int T[11], S[11], zoff[11], wsoff[11];
  int tileStart[12], instStart[12], rstart[11];
  float scale[11];
  int totTemp, totInst, totr;
};

__device__ __forceinline__ float bf2f(unsigned short u) {
  union { unsigned int i; float f; } v; v.i = ((unsigned int)u) << 16; return v.f;
}
__device__ __forceinline__ unsigned short f2bf(float f) {
  union { float f; unsigned int i; } u; u.f = f;
  unsigned int b = u.i + 0x7FFFu + ((u.i >> 16) & 1u);
  return (unsigned short)(b >> 16);
}

__device__ __forceinline__ const unsigned short* zrowb(
    const unsigned short* __restrict__ z1, const unsigned short* __restrict__ z2,
    int b, int T, int r) {
  return (r < T) ? (z1 + ((size_t)b * T + r) * D_DIM)
                 : (z2 + ((size_t)b * T + (r - T)) * D_DIM);
}

#define GLOAD_LDS16(SRC, DST)                                                   \
  __builtin_amdgcn_global_load_lds(                                             \
      (const __attribute__((address_space(1))) void*)(SRC),                     \
      (__attribute__((address_space(3))) void*)(DST), 16, 0, 0)

// ---------------- prep: fused [sortall (blocks 0..7)] + [convert+zero] -------
__global__ __launch_bounds__(1024) void prep_kernel(
    const int* __restrict__ time0, int* __restrict__ sel_all,
    const float* __restrict__ i1, const float* __restrict__ i2,
    unsigned short* __restrict__ o1, unsigned short* __restrict__ o2,
    int n4, float* __restrict__ out, int outn, int nconv) {
  int bx = blockIdx.x;
  int tid = threadIdx.x;

  if (bx < 8) {
    // ---------- all-levels stable sort + selection + time chain ----------
    int b = bx;
    int lane = tid & 63, wid = tid >> 6;
    __shared__ int tcur[1024];
    __shared__ unsigned long long kl[1024];
    __shared__ int wcnt[16];
    __shared__ int tnew[512];

    tcur[tid] = time0[b * 1024 + tid];
    __syncthreads();

    int off = 0;
    for (int T = 1024; T >= 2; T >>= 1) {
      int n = T - 1, half = T >> 1;
      unsigned long long key = ~0ULL;
      if (tid < n) {
        unsigned d = (unsigned)(tcur[tid + 1] - tcur[tid]);
        key = ((unsigned long long)d << 10) | (unsigned)tid;
      }
      for (int size = 2; size <= T; size <<= 1) {
        bool up = ((tid & size) == 0);
        for (int stride = size >> 1; stride > 0; stride >>= 1) {
          bool lower = ((tid & stride) == 0);
          bool takemin = (lower == up);
          if (stride >= 64) {
            if (tid < T) kl[tid] = key;
            __syncthreads();
            if (tid < T) {
              unsigned long long pk = kl[tid ^ stride];
              unsigned long long mn = key < pk ? key : pk;
              unsigned long long mx = key < pk ? pk : key;
              key = takemin ? mn : mx;
            }
            __syncthreads();
          } else {
            unsigned klo = (unsigned)key, khi = (unsigned)(key >> 32);
            unsigned plo = __shfl_xor((int)klo, stride);
            unsigned phi = __shfl_xor((int)khi, stride);
            unsigned long long pk = ((unsigned long long)phi << 32) | plo;
            unsigned long long mn = key < pk ? key : pk;
            unsigned long long mx = key < pk ? pk : key;
            key = takemin ? mn : mx;
          }
        }
      }
      int p = (int)(key & 1023ULL);
      bool mask = (tid < n) && (p < half);
      unsigned long long bal = __ballot(mask);
      int rw = __popcll(bal & ((1ull << lane) - 1ull));
      if (lane == 0) wcnt[wid] = (int)__popcll(bal);
      __syncthreads();
      int pre = 0;
      for (int i = 0; i < wid; ++i) pre += wcnt[i];
      if (mask) {
        int rank = pre + rw;
        sel_all[off + b * half + rank] = tid;
        tnew[rank] = (tcur[tid] + tcur[tid + 1]) >> 1;
      }
      __syncthreads();
      if (tid < half) tcur[tid] = tnew[tid];
      off += 8 * half;
      __syncthreads();
    }
  } else {
    // ---------- fp32 -> bf16 convert (both arrays) + zero out ----------
    int i = (bx - 8) * 1024 + tid;
    if (i < outn) out[i] = 0.f;
    int stride = nconv * 1024;
    for (int j = i; j < n4; j += stride) {
      float4 v = ((const float4*)i1)[j];
      ushort4 r;
      r.x = f2bf(v.x); r.y = f2bf(v.y); r.z = f2bf(v.z); r.w = f2bf(v.w);
      ((ushort4*)o1)[j] = r;
      float4 u = ((const float4*)i2)[j];
      ushort4 q;
      q.x = f2bf(u.x); q.y = f2bf(u.y); q.z = f2bf(u.z); q.w = f2bf(u.w);
      ((ushort4*)o2)[j] = q;
    }
  }
}

// ---------------- pool chain: LDS-resident d-slice, all 10 levels ----------
__global__ __launch_bounds__(256, 2) void poolchain_kernel(
    const int* __restrict__ sel_all,
    unsigned short* __restrict__ z1, unsigned short* __restrict__ z2) {
  int bx = blockIdx.x;
  int tid = threadIdx.x;
  int chunk = bx % 20;
  int zi = (bx / 20) & 1;
  int b = bx / 40;
  unsigned short* z = (zi == 0) ? z1 : z2;

  __shared__ unsigned short zsA[1024][18];
  __shared__ unsigned short zsB[512][18];

  const unsigned short* src0 = z + ((size_t)b * 1024) * D_DIM + chunk * 16;
  for (int u = tid; u < 1024 * 2; u += 256) {
    int r = u >> 1, h = u & 1;
    *(bf16x8_t*)&zsA[r][h * 8] = *(const bf16x8_t*)(src0 + (size_t)r * D_DIM + h * 8);
  }
  __syncthreads();

  int off = 0;
  size_t zo = (size_t)8 * 1024 * D_DIM;
  for (int l = 0; l < 10; ++l) {
    int T = 1024 >> l, half = T >> 1;
    const int* selp = sel_all + off + b * half;
    unsigned short* dst = z + zo + ((size_t)b * half) * D_DIM + chunk * 16;
    bool AtoB = ((l & 1) == 0);
    for (int u = tid; u < half * 2; u += 256) {
      int j = u >> 1, h = u & 1;
      int k = selp[j];
      bf16x8_t a, c;
      if (AtoB) {
        a = *(const bf16x8_t*)&zsA[k][h * 8];
        c = *(const bf16x8_t*)&zsA[k + 1][h * 8];
      } else {
        a = *(const bf16x8_t*)&zsB[k][h * 8];
        c = *(const bf16x8_t*)&zsB[k + 1][h * 8];
      }
      bf16x8_t rv;
#pragma unroll
      for (int e = 0; e < 8; ++e)
        rv[e] = (bf2f((unsigned short)a[e]) >= bf2f((unsigned short)c[e])) ? a[e] : c[e];
      *(bf16x8_t*)(dst + (size_t)j * D_DIM + h * 8) = rv;
      if (AtoB) *(bf16x8_t*)&zsB[j][h * 8] = rv;
      else      *(bf16x8_t*)&zsA[j][h * 8] = rv;
    }
    __syncthreads();
    off += 8 * half;
    zo += (size_t)8 * half * D_DIM;
  }
}

// ---------------- mega: symmetric temporal tiles + instance waves ----------
// temporal: only rb<=sg tiles; off-diag tiles emit row-LSE partials (seg sg)
// AND col-LSE partials (seg rb, via sim symmetry).
__global__ __launch_bounds__(256, 4) void mega_kernel(
    const unsigned short* __restrict__ z1, const unsigned short* __restrict__ z2,
    float* __restrict__ wsm, float* __restrict__ wss,
    float* __restrict__ out, Tab tab) {
  __shared__ __align__(16) unsigned char smem[36864];
  int bx = blockIdx.x;
  int tid = threadIdx.x;

  if (bx < tab.totTemp) {
    // ================= temporal tile (rb <= sg) =================
    int l = 0;
    while (bx >= tab.tileStart[l + 1]) ++l;
    int T = tab.T[l], S = tab.S[l];
    int N = 2 * T;
    const unsigned short* zz1 = z1 + tab.zoff[l];
    const unsigned short* zz2 = z2 + tab.zoff[l];
    float* wm = wsm + tab.wsoff[l];
    float* wv = wss + tab.wsoff[l];

    int local = bx - tab.tileStart[l];
    int npl = (S * (S + 1)) >> 1;
    int nid = (local % 8) * npl + local / 8;  // XCD x -> batch x (L2-resident)
    int b = nid / npl;
    int pr = nid % npl;
    int rb = 0, tt = pr;
    while (tt >= S - rb) { tt -= S - rb; ++rb; }
    int sg = rb + tt;
    int row0 = rb * 128, col0 = sg * 128;

    int w = tid >> 6, lane = tid & 63;
    int lq = lane >> 4, lr = lane & 15;
    int wr = w >> 1, wc = w & 1;

    unsigned short* lds = (unsigned short*)smem;            // 32768 B
    float (*mS)[128] = (float(*)[128])(smem + 32768);
    float (*sS)[128] = (float(*)[128])(smem + 33792);
    float (*mC)[128] = (float(*)[128])(smem + 34816);
    float (*sC)[128] = (float(*)[128])(smem + 35840);

    // hoisted per-wave global sources (rows/cols fixed; only K advances)
    int ra0 = row0 + lane;        if (ra0 > N - 1) ra0 = N - 1;
    int ra1 = row0 + 64 + lane;   if (ra1 > N - 1) ra1 = N - 1;
    int ca0 = col0 + lane;        if (ca0 > N - 1) ca0 = N - 1;
    int ca1 = col0 + 64 + lane;   if (ca1 > N - 1) ca1 = N - 1;
    const unsigned short* gA0 = zrowb(zz1, zz2, b, T, ra0) + w * 8;
    const unsigned short* gA1 = zrowb(zz1, zz2, b, T, ra1) + w * 8;
    const unsigned short* gB0 = zrowb(zz1, zz2, b, T, ca0) + w * 8;
    const unsigned short* gB1 = zrowb(zz1, zz2, b, T, ca1) + w * 8;
    unsigned short* dA0 = &lds[((w) * 128 + lane) * 8];
    unsigned short* dA1 = &lds[((w) * 128 + 64 + lane) * 8];
    unsigned short* dB0 = &lds[((4 + w) * 128 + lane) * 8];
    unsigned short* dB1 = &lds[((4 + w) * 128 + 64 + lane) * 8];

#define STAGE(koff, bufofs)                                                     \
    do {                                                                        \
      GLOAD_LDS16(gA0 + (koff), dA0 + (bufofs));                                \
      GLOAD_LDS16(gA1 + (koff), dA1 + (bufofs));                                \
      GLOAD_LDS16(gB0 + (koff), dB0 + (bufofs));                                \
      GLOAD_LDS16(gB1 + (koff), dB1 + (bufofs));                                \
    } while (0)

    f32x4_t acc[4][4];
#pragma unroll
    for (int at = 0; at < 4; ++at)
#pragma unroll
      for (int ct = 0; ct < 4; ++ct) acc[at][ct] = (f32x4_t)(0.f);

    const unsigned short* vA = &lds[((lq) * 128 + wr * 64 + lr) * 8];
    const unsigned short* vB = &lds[((4 + lq) * 128 + wc * 64 + lr) * 8];
#define BUFOFS 8192  /* shorts: 8 planes *128 rows *8 */

    STAGE(0, 0);
    STAGE(32, BUFOFS);

#define PHASE(k, bo, VM, DO_PF)                                                 \
    do {                                                                        \
      asm volatile("s_waitcnt vmcnt(" #VM ")" ::: "memory");                    \
      __builtin_amdgcn_s_barrier();                                             \
      bf16x8_t af[4], bfr[4];                                                   \
      _Pragma("unroll")                                                         \
      for (int at = 0; at < 4; ++at)                                            \
        af[at] = *(const bf16x8_t*)(vA + (bo) + at * 128);                      \
      _Pragma("unroll")                                                         \
      for (int ct = 0; ct < 4; ++ct)                                            \
        bfr[ct] = *(const bf16x8_t*)(vB + (bo) + ct * 128);                     \
      asm volatile("s_waitcnt lgkmcnt(0)" ::: "memory");                        \
      __builtin_amdgcn_sched_barrier(0);                                        \
      __builtin_amdgcn_s_barrier();                                             \
      if (DO_PF) STAGE((k + 2) * 32, bo);                                       \
      __builtin_amdgcn_s_setprio(1);                                            \
      _Pragma("unroll")                                                         \
      for (int ct = 0; ct < 4; ++ct)                                            \
        _Pragma("unroll")                                                       \
        for (int at = 0; at < 4; ++at)                                          \
          acc[at][ct] = __builtin_amdgcn_mfma_f32_16x16x32_bf16(                \
              af[at], bfr[ct], acc[at][ct], 0, 0, 0);                           \
      __builtin_amdgcn_s_setprio(0);                                            \
    } while (0)

    for (int k = 0; k < 8; k += 2) {
      PHASE(k, 0, 4, 1);
      PHASE(k + 1, BUFOFS, 4, 1);
    }
    PHASE(8, 0, 4, 0);
    PHASE(9, BUFOFS, 0, 0);
#undef PHASE
#undef STAGE
    __builtin_amdgcn_s_barrier();

    // ---- row-LSE over this tile's 128 cols -> partial for col-seg sg ----
#pragma unroll
    for (int at = 0; at < 4; ++at) {
#pragma unroll
      for (int rg = 0; rg < 4; ++rg) {
        int rloc = wr * 64 + at * 16 + lq * 4 + rg;
        int rglob = row0 + rloc;
        float v[4];
#pragma unroll
        for (int ct = 0; ct < 4; ++ct) {
          int cg = col0 + wc * 64 + ct * 16 + lr;
          v[ct] = (cg < N && cg != rglob) ? acc[at][ct][rg] : NEGINF;
        }
        float m = fmaxf(fmaxf(v[0], v[1]), fmaxf(v[2], v[3]));
#pragma unroll
        for (int o = 1; o < 16; o <<= 1) m = fmaxf(m, __shfl_xor(m, o));
        float sv = __expf(v[0] - m) + __expf(v[1] - m) +
                   __expf(v[2] - m) + __expf(v[3] - m);
#pragma unroll
        for (int o = 1; o < 16; o <<= 1) sv += __shfl_xor(sv, o);
        if (lr == 0) { mS[wc][rloc] = m; sS[wc][rloc] = sv; }
      }
    }

    // ---- col-LSE over this tile's 128 rows -> partial for col-seg rb ----
    if (rb != sg) {
      float mCr[4], sCr[4];
#pragma unroll
      for (int ct = 0; ct < 4; ++ct) {
        float m = NEGINF;
#pragma unroll
        for (int at = 0; at < 4; ++at)
#pragma unroll
          for (int rg = 0; rg < 4; ++rg) m = fmaxf(m, acc[at][ct][rg]);
        m = fmaxf(m, __shfl_xor(m, 16));
        m = fmaxf(m, __shfl_xor(m, 32));
        float s = 0.f;
#pragma unroll
        for (int at = 0; at < 4; ++at)
#pragma unroll
          for (int rg = 0; rg < 4; ++rg) s += __expf(acc[at][ct][rg] - m);
        s += __shfl_xor(s, 16);
        s += __shfl_xor(s, 32);
        mCr[ct] = m; sCr[ct] = s;
      }
      if (lq == 0) {
#pragma unroll
        for (int ct = 0; ct < 4; ++ct) {
          mC[wr][wc * 64 + ct * 16 + lr] = mCr[ct];
          sC[wr][wc * 64 + ct * 16 + lr] = sCr[ct];
        }
      }
    }
    __syncthreads();

    if (tid < 128) {
      int rglob = row0 + tid;
      if (rglob < N) {
        float m0 = mS[0][tid], m1 = mS[1][tid];
        float m = fmaxf(m0, m1);
        float sv = sS[0][tid] * __expf(m0 - m) + sS[1][tid] * __expf(m1 - m);
        int idx = (b * S + sg) * N + rglob;
        wm[idx] = m;
        wv[idx] = sv;
      }
      if (rb != sg) {
        float m0 = mC[0][tid], m1 = mC[1][tid];
        float m = fmaxf(m0, m1);
        float sv = sC[0][tid] * __expf(m0 - m) + sC[1][tid] * __expf(m1 - m);
        int idx = (b * S + rb) * N + col0 + tid;
        wm[idx] = m;
        wv[idx] = sv;
      }
    }
  } else {
    // ================= instance loss: one wave per t, MFMA Z·Z^T =============
    float wsum = 0.f;
    int iw = (bx - tab.totTemp) * 4 + (tid >> 6);
    if (iw < tab.totInst) {
      int l = 0;
      while (iw >= tab.instStart[l + 1]) ++l;
      int t = iw - tab.instStart[l];
      int T = tab.T[l];
      const unsigned short* zz1 = z1 + tab.zoff[l];
      const unsigned short* zz2 = z2 + tab.zoff[l];
      int lane = tid & 63, lq = lane >> 4, lr = lane & 15;
      const unsigned short* zr = (lr < 8)
          ? zz1 + ((size_t)lr * T + t) * D_DIM
          : zz2 + ((size_t)(lr - 8) * T + t) * D_DIM;
      zr += lq * 8;
      f32x4_t c = (f32x4_t)(0.f);
#pragma unroll
      for (int k = 0; k < 10; ++k) {
        bf16x8_t a = *(const bf16x8_t*)(zr + k * 32);
        c = __builtin_amdgcn_mfma_f32_16x16x32_bf16(a, a, c, 0, 0, 0);
      }
      float lsum = 0.f;
#pragma unroll
      for (int rg = 0; rg < 4; ++rg) {
        int rrow = lq * 4 + rg;
        float v = c[rg];
        float x = (lr != rrow) ? v : NEGINF;
        float m = x;
#pragma unroll
        for (int o = 1; o < 16; o <<= 1) m = fmaxf(m, __shfl_xor(m, o));
        float s = __expf(x - m);
#pragma unroll
        for (int o = 1; o < 16; o <<= 1) s += __shfl_xor(s, o);
        int pos = (rrow < 8) ? rrow + 8 : rrow - 8;
        if (lr == pos) lsum += m + __logf(s) - v;
      }
#pragma unroll
      for (int o = 1; o < 64; o <<= 1) lsum += __shfl_xor(lsum, o);
      wsum = lsum * tab.scale[l];
    }
    float* part = (float*)smem;
    if ((tid & 63) == 0) part[tid >> 6] = wsum;
    __syncthreads();
    if (tid == 0)
      atomicAdd(out, part[0] + part[1] + part[2] + part[3]);
  }
}

// ---------------- combine all levels' temporal partials, one launch ----------
__global__ __launch_bounds__(256) void combine_kernel(
    const unsigned short* __restrict__ z1, const unsigned short* __restrict__ z2,
    const float* __restrict__ wsm, const float* __restrict__ wss,
    float* __restrict__ out, Tab tab) {
  int g = blockIdx.x * 256 + threadIdx.x;
  float loss = 0.f;
  if (g < tab.totr) {
    int l = 0;
    while (g >= tab.rstart[l + 1]) ++l;
    int row = g - tab.rstart[l];
    int T = tab.T[l], N = 2 * T, S = tab.S[l];
    int b = row / N, r = row % N;
    const float* wm = wsm + tab.wsoff[l];
    const float* wv = wss + tab.wsoff[l];
    float m = NEGINF;
    for (int s = 0; s < S; ++s) m = fmaxf(m, wm[(b * S + s) * N + r]);
    float sv = 0.f;
    for (int s = 0; s < S; ++s) {
      int idx = (b * S + s) * N + r;
      sv += wv[idx] * __expf(wm[idx] - m);
    }
    const unsigned short* zz1 = z1 + tab.zoff[l];
    const unsigned short* zz2 = z2 + tab.zoff[l];
    int pos = (r < T) ? r + T : r - T;
    const bf16x8_t* za = (const bf16x8_t*)zrowb(zz1, zz2, b, T, r);
    const bf16x8_t* zp = (const bf16x8_t*)zrowb(zz1, zz2, b, T, pos);
    float dot = 0.f;
    for (int k = 0; k < D_DIM / 8; ++k) {
      bf16x8_t a = za[k], p = zp[k];
#pragma unroll
      for (int e = 0; e < 8; ++e)
        dot += bf2f((unsigned short)a[e]) * bf2f((unsigned short)p[e]);
    }
    loss = (m + logf(sv) - dot) * tab.scale[l];
  }
  float v = loss;
#pragma unroll
  for (int o = 1; o < 64; o <<= 1) v += __shfl_xor(v, o);
  __shared__ float part[4];
  int w = threadIdx.x >> 6;
  if ((threadIdx.x & 63) == 0) part[w] = v;
  __syncthreads();
  if (threadIdx.x == 0)
    atomicAdd(out, part[0] + part[1] + part[2] + part[3]);
}

extern "C" void kernel_launch(void* const* d_in, const int* in_sizes, int n_in,
                              void* d_out, int out_size, void* d_ws, size_t ws_size,
                              hipStream_t stream) {
  const float* z1_in = (const float*)d_in[0];
  const float* z2_in = (const float*)d_in[1];
  const int* time_in = (const int*)d_in[2];
  float* out = (float*)d_out;

  // ---- build level tables (triangular tile counts) ----
  Tab tab;
  int zo = 0, wso = 0, ts = 0, is = 0, rs = 0;
  for (int l = 0; l < 11; ++l) {
    int T = 1024 >> l, N = 2 * T;
    int S = (N >= 128) ? N / 128 : 1;
    tab.T[l] = T;
    tab.S[l] = S;
    tab.zoff[l] = zo;
    tab.scale[l] = 1.0f / (352.0f * (float)T);  // 0.5/(2*B*T)/11
    tab.tileStart[l] = ts;
    tab.instStart[l] = is;
    tab.wsoff[l] = (T > 1) ? wso : 0;
    if (l < 10) tab.rstart[l] = rs;
    if (T > 1) {
      ts += 8 * ((S * (S + 1)) >> 1);
      wso += 8 * S * N;
      rs += 8 * N;
    }
    is += T;
    zo += 8 * T * D_DIM;
  }
  tab.tileStart[11] = ts;
  tab.instStart[11] = is;
  tab.rstart[10] = rs;
  tab.totTemp = ts;
  tab.totInst = is;
  tab.totr = rs;

  // ---- workspace carve ----
  char* w = (char*)d_ws;
  unsigned short* z1s = (unsigned short*)w; w += (size_t)zo * 2;
  unsigned short* z2s = (unsigned short*)w; w += (size_t)zo * 2;
  int* sel_all = (int*)w; w += 8192 * sizeof(int);
  float* wsm = (float*)w; w += (size_t)wso * sizeof(float);
  float* wss = (float*)w; w += (size_t)wso * sizeof(float);

  int n0 = 8 * 1024 * D_DIM;
  int nconv = 504;
  prep_kernel<<<8 + nconv, 1024, 0, stream>>>(time_in, sel_all, z1_in, z2_in,
                                              z1s, z2s, n0 / 4, out, out_size,
                                              nconv);
  poolchain_kernel<<<320, 256, 0, stream>>>(sel_all, z1s, z2s);
  int nInstB = (is + 3) / 4;
  mega_kernel<<<ts + nInstB, 256, 0, stream>>>(z1s, z2s, wsm, wss, out, tab);
  combine_kernel<<<(rs + 255) / 256, 256, 0, stream>>>(z1s, z2s, wsm, wss, out, tab);
}